// Round 1
// 316.615 us; speedup vs baseline: 1.0947x; 1.0947x over previous
//
#include <hip/hip_runtime.h>
#include <hip/hip_bf16.h>
#include <math.h>

typedef unsigned short ushort_t;
typedef unsigned int uint_t;

// Problem constants
#define BB 32
#define PP 6
#define DD 96
#define EE 128
#define HH 8
#define II 64
#define KK 32
#define LSEQ 768            // N*D
#define ROWS (BB * LSEQ)    // 24576 token rows
#define OUTN 128
#define KOUT (LSEQ * EE)    // 98304

using bf16x8 = __attribute__((ext_vector_type(8))) short;
using bf16x4 = __attribute__((ext_vector_type(4))) short;
using f32x4  = __attribute__((ext_vector_type(4))) float;
using u32x4  = __attribute__((ext_vector_type(4))) uint_t;

__device__ __forceinline__ ushort_t f2b(float f) {
    __hip_bfloat16 h = __float2bfloat16(f);
    return *reinterpret_cast<ushort_t*>(&h);
}
// pack two fp32 -> (bf16(hi)<<16)|bf16(lo) by TRUNCATION: one v_perm_b32.
__device__ __forceinline__ uint_t permpack(float hi, float lo) {
    return __builtin_amdgcn_perm(__builtin_bit_cast(uint_t, hi),
                                 __builtin_bit_cast(uint_t, lo), 0x07060302u);
}

// ---------------------------------------------------------------------------
// Cast fp32 -> bf16 (four weight tensors) + positional-encoding table, one
// launch. PE table: 768 x 128 fp32 (computed once here, read by embed -> the
// 3.1M-thread embed kernel loses its per-thread precise sinf/cosf/expf).
// ---------------------------------------------------------------------------
__global__ void cast_all_kernel(
    const float* __restrict__ s0, int n0, const float* __restrict__ s1, int n1,
    const float* __restrict__ s2, int n2, const float* __restrict__ s3, int n3,
    ushort_t* __restrict__ d0, ushort_t* __restrict__ d1,
    ushort_t* __restrict__ d2, ushort_t* __restrict__ d3,
    float* __restrict__ peT)
{
    int i = blockIdx.x * 256 + threadIdx.x;
    if (i < n0) { d0[i] = f2b(s0[i]); return; }
    i -= n0;
    if (i < n1) { d1[i] = f2b(s1[i]); return; }
    i -= n1;
    if (i < n2) { d2[i] = f2b(s2[i]); return; }
    i -= n2;
    if (i < n3) { d3[i] = f2b(s3[i]); return; }
    i -= n3;
    // PE table: i in [0, LSEQ*EE)
    const int lpos = i >> 7, tt = i & 127;
    const float twoj = (float)((tt >> 1) * 2);
    const float div = __expf(twoj * (-9.210340371976184f / 128.0f));
    const float ang = (float)lpos * div;
    peT[i] = (tt & 1) ? __cosf(ang) : __sinf(ang);
}

// ---------------------------------------------------------------------------
// Embed: PE now comes from the precomputed table (one coalesced load).
// ---------------------------------------------------------------------------
__global__ __launch_bounds__(128) void embed_kernel(
    const float* __restrict__ x, const float* __restrict__ prot,
    const float* __restrict__ emb_w, const float* __restrict__ emb_b,
    const float* __restrict__ proj_w, const float* __restrict__ proj_b,
    const float* __restrict__ peT,
    float* __restrict__ seq, ushort_t* __restrict__ seq_bf)
{
    const int r = blockIdx.x;
    const int t = threadIdx.x;
    __shared__ float xrow[PP];
    __shared__ float sel[PP];

    if (t < PP) xrow[t] = x[r * PP + t];
    __syncthreads();

    float nx = 0.f;
    #pragma unroll
    for (int p = 0; p < PP; ++p) nx += xrow[p] * xrow[p];
    const float xinv = 1.f / fmaxf(sqrtf(nx), 1e-12f);

    const int d = r % DD;
    if (t < KK) {
        const float* pr = prot + (d * KK + t) * PP;
        float pp[PP];
        float np2 = 0.f;
        #pragma unroll
        for (int p = 0; p < PP; ++p) { pp[p] = pr[p]; np2 += pp[p] * pp[p]; }
        const float pinv = 1.f / fmaxf(sqrtf(np2), 1e-12f);
        float dot = 0.f;
        #pragma unroll
        for (int p = 0; p < PP; ++p) dot += xrow[p] * pp[p];
        float sim = dot * xinv * pinv;
        int k = t;
        #pragma unroll
        for (int off = 16; off; off >>= 1) {
            float osim = __shfl_down(sim, off);
            int   ok   = __shfl_down(k, off);
            if (osim > sim || (osim == sim && ok < k)) { sim = osim; k = ok; }
        }
        k = __shfl(k, 0);
        if (t == k) {
            #pragma unroll
            for (int p = 0; p < PP; ++p) sel[p] = pp[p] * pinv;
        }
    }
    __syncthreads();

    float acc = emb_b[t] + proj_b[t];
    #pragma unroll
    for (int p = 0; p < PP; ++p) acc = fmaf(xrow[p], emb_w[t * PP + p], acc);
    #pragma unroll
    for (int p = 0; p < PP; ++p) acc = fmaf(sel[p], proj_w[t * PP + p], acc);

    const int lpos = r % LSEQ;
    const float v = acc + peT[lpos * EE + t];
    seq[(size_t)r * EE + t] = v;
    seq_bf[(size_t)r * EE + t] = f2b(v);
}

// ---------------------------------------------------------------------------
// Direct-activation MFMA GEMM (swapped operands).
// flags: 1 = ELU; 2 = bf16 out; 4 = scale n<128 by 0.25*log2(e) (Q pre-scale,
// log2e folded in so attention can use raw v_exp/exp2 instead of __expf).
// ---------------------------------------------------------------------------
__global__ __launch_bounds__(256) void gemm_direct(
    const ushort_t* __restrict__ A, const ushort_t* __restrict__ W,
    const float* __restrict__ bias, void* __restrict__ Cout,
    int M, int N, int K, int flags)
{
    __shared__ ushort_t Ws[64 * 136];   // kp = K+8 <= 136
    const int t = threadIdx.x;
    const int wave = t >> 6, lane = t & 63;
    const int quad = lane >> 4, l16 = lane & 15;
    const int m0 = blockIdx.y * 128, n0 = blockIdx.x * 64;
    const int kp = K + 8;
    const int ak8 = K >> 3;

    for (int c = t; c < 64 * ak8; c += 256) {
        int row = c / ak8, col = c - row * ak8;
        *(bf16x8*)&Ws[row * kp + col * 8] =
            *(const bf16x8*)&W[(size_t)(n0 + row) * K + col * 8];
    }
    __syncthreads();

    f32x4 acc[2][4];
    #pragma unroll
    for (int s = 0; s < 2; ++s)
        #pragma unroll
        for (int nt = 0; nt < 4; ++nt)
            acc[s][nt] = (f32x4){0.f, 0.f, 0.f, 0.f};

    const ushort_t* a0p = A + (size_t)(m0 + wave * 32 + l16) * K + quad * 8;
    const ushort_t* a1p = a0p + (size_t)16 * K;
    const ushort_t* wp  = &Ws[l16 * kp + quad * 8];

    for (int k0 = 0; k0 < K; k0 += 32) {
        bf16x8 a0 = *(const bf16x8*)(a0p + k0);
        bf16x8 a1 = *(const bf16x8*)(a1p + k0);
        #pragma unroll
        for (int nt = 0; nt < 4; ++nt) {
            bf16x8 wf = *(const bf16x8*)(wp + nt * 16 * kp + k0);
            acc[0][nt] = __builtin_amdgcn_mfma_f32_16x16x32_bf16(wf, a0, acc[0][nt], 0, 0, 0);
            acc[1][nt] = __builtin_amdgcn_mfma_f32_16x16x32_bf16(wf, a1, acc[1][nt], 0, 0, 0);
        }
    }

    #pragma unroll
    for (int s = 0; s < 2; ++s) {
        const int m = m0 + wave * 32 + s * 16 + l16;
        #pragma unroll
        for (int nt = 0; nt < 4; ++nt) {
            const int nb = n0 + nt * 16 + quad * 4;
            float4 b4 = *(const float4*)&bias[nb];
            float v[4];
            #pragma unroll
            for (int r = 0; r < 4; ++r) {
                v[r] = acc[s][nt][r] + ((const float*)&b4)[r];
                if (flags & 1) v[r] = v[r] > 0.f ? v[r] : expm1f(v[r]);
            }
            if ((flags & 4) && nb < EE) {
                #pragma unroll
                for (int r = 0; r < 4; ++r) v[r] *= 0.36067376022224085f; // 0.25*log2(e)
            }
            if (flags & 2) {
                uint2 w2;
                w2.x = permpack(v[1], v[0]);
                w2.y = permpack(v[3], v[2]);
                *(uint2*)&((ushort_t*)Cout)[(size_t)m * N + nb] = w2;
            } else {
                float4 f4 = {v[0], v[1], v[2], v[3]};
                *(float4*)&((float*)Cout)[(size_t)m * N + nb] = f4;
            }
        }
    }
}

// ---------------------------------------------------------------------------
// MFMA flash attention v6: VALU-diet inner loop.
//  - Q pre-scaled by 0.25*log2e -> exp is a single v_exp (exp2), no v_mul.
//  - row-sum of P via a third MFMA against a ones-fragment: D[i,j]=sum_k P[k,j]
//    is row-replicated, so lacc[s][0] holds the FULLY-reduced softmax denom
//    (kills 4 v_add per iter AND the epilogue shfl_xor pair).
//  - V-fragment prefetched one chunk ahead like K.
// Per 16-chunk per s: 3 MFMA + 6 VALU (was 2 MFMA + 14 VALU).
// ---------------------------------------------------------------------------
#define VTS 792
__global__ __launch_bounds__(512) void attention_mfma(
    const ushort_t* __restrict__ qkv, ushort_t* __restrict__ ctx)
{
    __shared__ ushort_t Vt[16 * VTS];

    const int bh = blockIdx.x;
    const int b = bh & 31, h = bh >> 5;     // XCD swizzle: id%8 == b%8
    const int qb = blockIdx.y * 256;
    const int t = threadIdx.x;
    const int wave = t >> 6, lane = t & 63;
    const int quad = lane >> 4, l16 = lane & 15;
    const size_t bbase = (size_t)b * LSEQ * 384;
    const int hoff = h * 16;

    // ---- stage V transposed ----
    for (int idx = t; idx < 1536; idx += 512) {
        int row = idx >> 1, half = idx & 1;
        bf16x8 v = *(const bf16x8*)&qkv[bbase + (size_t)row * 384 + 2 * EE + hoff + half * 8];
        #pragma unroll
        for (int j = 0; j < 8; ++j)
            Vt[(half * 8 + j) * VTS + row] = (ushort_t)v[j];
    }

    // ---- Q fragments ----
    bf16x4 qf[2];
    #pragma unroll
    for (int s = 0; s < 2; ++s) {
        int row = qb + wave * 32 + s * 16 + l16;
        qf[s] = *(const bf16x4*)&qkv[bbase + (size_t)row * 384 + hoff + quad * 4];
    }
    __syncthreads();

    f32x4 oacc[2], lacc[2];
    oacc[0] = (f32x4){0.f, 0.f, 0.f, 0.f};
    oacc[1] = (f32x4){0.f, 0.f, 0.f, 0.f};
    lacc[0] = (f32x4){0.f, 0.f, 0.f, 0.f};
    lacc[1] = (f32x4){0.f, 0.f, 0.f, 0.f};
    const f32x4 zero4 = (f32x4){0.f, 0.f, 0.f, 0.f};
    bf16x4 ones4;
    #pragma unroll
    for (int j = 0; j < 4; ++j) ones4[j] = (short)0x3F80;   // bf16 1.0

    const ushort_t* kbase = qkv + bbase + EE + hoff + quad * 4;

    bf16x4 kf = *(const bf16x4*)&kbase[(size_t)l16 * 384];       // prefetch ch=0
    bf16x4 vf = *(const bf16x4*)&Vt[l16 * VTS + quad * 4];       // prefetch ch=0

    for (int ch = 0; ch < LSEQ; ch += 16) {
        bf16x4 kf_n = kf, vf_n = vf;
        if (ch + 16 < LSEQ) {
            kf_n = *(const bf16x4*)&kbase[(size_t)(ch + 16 + l16) * 384];
            vf_n = *(const bf16x4*)&Vt[l16 * VTS + (ch + 16) + quad * 4];
        }

        #pragma unroll
        for (int s = 0; s < 2; ++s) {
            f32x4 sv = __builtin_amdgcn_mfma_f32_16x16x16bf16_1k(kf, qf[s], zero4, 0, 0, 0);
            float e0 = __builtin_amdgcn_exp2f(sv[0]);
            float e1 = __builtin_amdgcn_exp2f(sv[1]);
            float e2 = __builtin_amdgcn_exp2f(sv[2]);
            float e3 = __builtin_amdgcn_exp2f(sv[3]);
            uint2 pu;
            pu.x = permpack(e1, e0);
            pu.y = permpack(e3, e2);
            bf16x4 pf = __builtin_bit_cast(bf16x4, pu);
            oacc[s] = __builtin_amdgcn_mfma_f32_16x16x16bf16_1k(vf, pf, oacc[s], 0, 0, 0);
            lacc[s] = __builtin_amdgcn_mfma_f32_16x16x16bf16_1k(ones4, pf, lacc[s], 0, 0, 0);
        }
        kf = kf_n;
        vf = vf_n;
    }

    #pragma unroll
    for (int s = 0; s < 2; ++s) {
        const float inv = 1.f / lacc[s][0];     // row-replicated full sum
        const int q = qb + wave * 32 + s * 16 + l16;
        uint2 w2;
        w2.x = permpack(oacc[s][1] * inv, oacc[s][0] * inv);
        w2.y = permpack(oacc[s][3] * inv, oacc[s][2] * inv);
        *(uint2*)&ctx[((size_t)(b * LSEQ + q)) * EE + hoff + quad * 4] = w2;
    }
}

// ---------------------------------------------------------------------------
// Direct-activation GEMM + residual + LayerNorm (N=128). (unchanged)
// ---------------------------------------------------------------------------
__global__ __launch_bounds__(256) void gemm_ln_direct(
    const ushort_t* __restrict__ A, const ushort_t* __restrict__ W,
    const float* __restrict__ bias,
    const float* __restrict__ gamma, const float* __restrict__ beta,
    float* __restrict__ seq, ushort_t* __restrict__ seq_bf, int K)
{
    __shared__ ushort_t Ws[128 * 136];
    const int t = threadIdx.x;
    const int wave = t >> 6, lane = t & 63;
    const int quad = lane >> 4, l16 = lane & 15;
    const int m0 = blockIdx.x * 64;
    const int kp = K + 8;
    const int ak8 = K >> 3;

    for (int c = t; c < 128 * ak8; c += 256) {
        int row = c / ak8, col = c - row * ak8;
        *(bf16x8*)&Ws[row * kp + col * 8] =
            *(const bf16x8*)&W[(size_t)row * K + col * 8];
    }
    __syncthreads();

    f32x4 acc[8];
    #pragma unroll
    for (int nt = 0; nt < 8; ++nt) acc[nt] = (f32x4){0.f, 0.f, 0.f, 0.f};

    const int m = m0 + wave * 16 + l16;
    const ushort_t* ap = A + (size_t)m * K + quad * 8;
    const ushort_t* wp = &Ws[l16 * kp + quad * 8];

    for (int k0 = 0; k0 < K; k0 += 32) {
        bf16x8 a = *(const bf16x8*)(ap + k0);
        #pragma unroll
        for (int nt = 0; nt < 8; ++nt) {
            bf16x8 wf = *(const bf16x8*)(wp + nt * 16 * kp + k0);
            acc[nt] = __builtin_amdgcn_mfma_f32_16x16x32_bf16(wf, a, acc[nt], 0, 0, 0);
        }
    }

    float v[8][4];
    float s = 0.f;
    #pragma unroll
    for (int nt = 0; nt < 8; ++nt) {
        const int nb = nt * 16 + quad * 4;
        float4 b4 = *(const float4*)&bias[nb];
        float4 r4 = *(const float4*)&seq[(size_t)m * EE + nb];
        #pragma unroll
        for (int r = 0; r < 4; ++r) {
            v[nt][r] = acc[nt][r] + ((const float*)&b4)[r] + ((const float*)&r4)[r];
            s += v[nt][r];
        }
    }
    s += __shfl_xor(s, 16);
    s += __shfl_xor(s, 32);
    const float mean = s * (1.f / 128.f);
    float s2 = 0.f;
    #pragma unroll
    for (int nt = 0; nt < 8; ++nt)
        #pragma unroll
        for (int r = 0; r < 4; ++r) {
            float d = v[nt][r] - mean;
            s2 += d * d;
        }
    s2 += __shfl_xor(s2, 16);
    s2 += __shfl_xor(s2, 32);
    const float rstd = 1.f / sqrtf(s2 * (1.f / 128.f) + 1e-5f);

    #pragma unroll
    for (int nt = 0; nt < 8; ++nt) {
        const int nb = nt * 16 + quad * 4;
        float4 g4 = *(const float4*)&gamma[nb];
        float4 be4 = *(const float4*)&beta[nb];
        float y[4];
        #pragma unroll
        for (int r = 0; r < 4; ++r)
            y[r] = (v[nt][r] - mean) * rstd * ((const float*)&g4)[r] + ((const float*)&be4)[r];
        float4 f4 = {y[0], y[1], y[2], y[3]};
        *(float4*)&seq[(size_t)m * EE + nb] = f4;
        uint2 w2;
        w2.x = permpack(y[1], y[0]);
        w2.y = permpack(y[3], y[2]);
        *(uint2*)&seq_bf[(size_t)m * EE + nb] = w2;
    }
}

// ---------------------------------------------------------------------------
// Fused FFN (unchanged).
// ---------------------------------------------------------------------------
__global__ __launch_bounds__(256) void ffn_fused(
    const ushort_t* __restrict__ seq_bf_in, const ushort_t* __restrict__ W1,
    const float* __restrict__ b1, const ushort_t* __restrict__ W2,
    const float* __restrict__ b2,
    const float* __restrict__ gamma, const float* __restrict__ beta,
    float* __restrict__ seq, ushort_t* __restrict__ seq_bf)
{
    __shared__ ushort_t W1s[64 * 136];
    __shared__ ushort_t W2s[128 * 72];
    __shared__ ushort_t Hs[64 * 72];
    const int t = threadIdx.x;
    const int wave = t >> 6, lane = t & 63;
    const int quad = lane >> 4, l16 = lane & 15;
    const int m0 = blockIdx.x * 64;

    for (int c = t; c < 64 * 16; c += 256) {
        int row = c >> 4, col = c & 15;
        *(bf16x8*)&W1s[row * 136 + col * 8] =
            *(const bf16x8*)&W1[(size_t)row * 128 + col * 8];
    }
    for (int c = t; c < 128 * 8; c += 256) {
        int row = c >> 3, col = c & 7;
        *(bf16x8*)&W2s[row * 72 + col * 8] =
            *(const bf16x8*)&W2[(size_t)row * 64 + col * 8];
    }
    __syncthreads();

    const int lrow = wave * 16 + l16;
    const int m = m0 + lrow;
    f32x4 acc1[4];
    #pragma unroll
    for (int nt = 0; nt < 4; ++nt) acc1[nt] = (f32x4){0.f, 0.f, 0.f, 0.f};

    const ushort_t* ap = seq_bf_in + (size_t)m * EE + quad * 8;
    const ushort_t* w1p = &W1s[l16 * 136 + quad * 8];
    for (int k0 = 0; k0 < 128; k0 += 32) {
        bf16x8 a = *(const bf16x8*)(ap + k0);
        #pragma unroll
        for (int nt = 0; nt < 4; ++nt) {
            bf16x8 wf = *(const bf16x8*)(w1p + nt * 16 * 136 + k0);
            acc1[nt] = __builtin_amdgcn_mfma_f32_16x16x32_bf16(wf, a, acc1[nt], 0, 0, 0);
        }
    }
    #pragma unroll
    for (int nt = 0; nt < 4; ++nt) {
        const int ib = nt * 16 + quad * 4;
        float4 b4 = *(const float4*)&b1[ib];
        float hv[4];
        #pragma unroll
        for (int r = 0; r < 4; ++r) {
            float u = acc1[nt][r] + ((const float*)&b4)[r];
            hv[r] = u > 0.f ? u : expm1f(u);
        }
        uint2 w2;
        w2.x = permpack(hv[1], hv[0]);
        w2.y = permpack(hv[3], hv[2]);
        *(uint2*)&Hs[lrow * 72 + ib] = w2;
    }

    f32x4 acc2[8];
    #pragma unroll
    for (int nt = 0; nt < 8; ++nt) acc2[nt] = (f32x4){0.f, 0.f, 0.f, 0.f};
    const ushort_t* hp = &Hs[lrow * 72 + quad * 8];
    const ushort_t* w2p = &W2s[l16 * 72 + quad * 8];
    #pragma unroll
    for (int k0 = 0; k0 < 64; k0 += 32) {
        bf16x8 hf = *(const bf16x8*)(hp + k0);
        #pragma unroll
        for (int nt = 0; nt < 8; ++nt) {
            bf16x8 wf = *(const bf16x8*)(w2p + nt * 16 * 72 + k0);
            acc2[nt] = __builtin_amdgcn_mfma_f32_16x16x32_bf16(wf, hf, acc2[nt], 0, 0, 0);
        }
    }

    float v[8][4];
    float s = 0.f;
    #pragma unroll
    for (int nt = 0; nt < 8; ++nt) {
        const int nb = nt * 16 + quad * 4;
        float4 b4 = *(const float4*)&b2[nb];
        float4 r4 = *(const float4*)&seq[(size_t)m * EE + nb];
        #pragma unroll
        for (int r = 0; r < 4; ++r) {
            v[nt][r] = acc2[nt][r] + ((const float*)&b4)[r] + ((const float*)&r4)[r];
            s += v[nt][r];
        }
    }
    s += __shfl_xor(s, 16);
    s += __shfl_xor(s, 32);
    const float mean = s * (1.f / 128.f);
    float s2 = 0.f;
    #pragma unroll
    for (int nt = 0; nt < 8; ++nt)
        #pragma unroll
        for (int r = 0; r < 4; ++r) {
            float d = v[nt][r] - mean;
            s2 += d * d;
        }
    s2 += __shfl_xor(s2, 16);
    s2 += __shfl_xor(s2, 32);
    const float rstd = 1.f / sqrtf(s2 * (1.f / 128.f) + 1e-5f);

    #pragma unroll
    for (int nt = 0; nt < 8; ++nt) {
        const int nb = nt * 16 + quad * 4;
        float4 g4 = *(const float4*)&gamma[nb];
        float4 be4 = *(const float4*)&beta[nb];
        float y[4];
        #pragma unroll
        for (int r = 0; r < 4; ++r)
            y[r] = (v[nt][r] - mean) * rstd * ((const float*)&g4)[r] + ((const float*)&be4)[r];
        float4 f4 = {y[0], y[1], y[2], y[3]};
        *(float4*)&seq[(size_t)m * EE + nb] = f4;
        uint2 w2;
        w2.x = permpack(y[1], y[0]);
        w2.y = permpack(y[3], y[2]);
        *(uint2*)&seq_bf[(size_t)m * EE + nb] = w2;
    }
}

// ---------------------------------------------------------------------------
// Final projection, split-K MFMA (unchanged).
// ---------------------------------------------------------------------------
#define PKC 192
#define PNBLK (KOUT / PKC)   // 512
__global__ __launch_bounds__(256) void out_gemm3(
    const ushort_t* __restrict__ seqbf, const float* __restrict__ out_w,
    float* __restrict__ part)
{
    const int t = threadIdx.x;
    const int wave = t >> 6, lane = t & 63;
    const int quad = lane >> 4, l16 = lane & 15;
    const size_t k0 = (size_t)blockIdx.x * PKC;
    const int n0 = wave * 32;

    f32x4 acc[2][2];
    #pragma unroll
    for (int mt = 0; mt < 2; ++mt)
        #pragma unroll
        for (int nt = 0; nt < 2; ++nt)
            acc[mt][nt] = (f32x4){0.f, 0.f, 0.f, 0.f};

    const ushort_t* a0p = seqbf + (size_t)l16 * KOUT + k0 + quad * 8;
    const ushort_t* a1p = a0p + (size_t)16 * KOUT;
    const float* w0p = out_w + (size_t)(n0 + l16) * KOUT + k0 + quad * 8;
    const float* w1p = w0p + (size_t)16 * KOUT;

    #pragma unroll
    for (int ks = 0; ks < PKC; ks += 32) {
        bf16x8 a0 = *(const bf16x8*)(a0p + ks);
        bf16x8 a1 = *(const bf16x8*)(a1p + ks);
        float4 wa0 = *(const float4*)(w0p + ks);
        float4 wa1 = *(const float4*)(w0p + ks + 4);
        float4 wb0 = *(const float4*)(w1p + ks);
        float4 wb1 = *(const float4*)(w1p + ks + 4);
        u32x4 b0, b1;
        b0[0] = permpack(wa0.y, wa0.x); b0[1] = permpack(wa0.w, wa0.z);
        b0[2] = permpack(wa1.y, wa1.x); b0[3] = permpack(wa1.w, wa1.z);
        b1[0] = permpack(wb0.y, wb0.x); b1[1] = permpack(wb0.w, wb0.z);
        b1[2] = permpack(wb1.y, wb1.x); b1[3] = permpack(wb1.w, wb1.z);
        bf16x8 bf0 = __builtin_bit_cast(bf16x8, b0);
        bf16x8 bf1 = __builtin_bit_cast(bf16x8, b1);
        acc[0][0] = __builtin_amdgcn_mfma_f32_16x16x32_bf16(a0, bf0, acc[0][0], 0, 0, 0);
        acc[1][0] = __builtin_amdgcn_mfma_f32_16x16x32_bf16(a1, bf0, acc[1][0], 0, 0, 0);
        acc[0][1] = __builtin_amdgcn_mfma_f32_16x16x32_bf16(a0, bf1, acc[0][1], 0, 0, 0);
        acc[1][1] = __builtin_amdgcn_mfma_f32_16x16x32_bf16(a1, bf1, acc[1][1], 0, 0, 0);
    }

    float* pb = part + (size_t)blockIdx.x * (32 * 128);
    #pragma unroll
    for (int mt = 0; mt < 2; ++mt)
        #pragma unroll
        for (int nt = 0; nt < 2; ++nt)
            #pragma unroll
            for (int r = 0; r < 4; ++r)
                pb[(mt * 16 + quad * 4 + r) * 128 + n0 + nt * 16 + l16] = acc[mt][nt][r];
}

// ---------------------------------------------------------------------------
// Two-stage partial reduction. Stage 1: 128 blocks (was 16) each sum 64 of
// the 512 split-K partials -> 8x parallelism on the 8 MB read. Stage 2: tiny.
// ---------------------------------------------------------------------------
__global__ __launch_bounds__(256) void out_reduce1(
    const float* __restrict__ part, float* __restrict__ part2)
{
    const int g = blockIdx.x & 15, rr = blockIdx.x >> 4;   // rr in 0..7
    const int i = g * 256 + threadIdx.x;
    const float* p = part + (size_t)rr * 64 * 4096 + i;
    float s0 = 0.f, s1 = 0.f, s2 = 0.f, s3 = 0.f;
    for (int blk = 0; blk < 64; blk += 4) {
        s0 += p[(size_t)blk * 4096];
        s1 += p[(size_t)(blk + 1) * 4096];
        s2 += p[(size_t)(blk + 2) * 4096];
        s3 += p[(size_t)(blk + 3) * 4096];
    }
    part2[rr * 4096 + i] = (s0 + s1) + (s2 + s3);
}

__global__ __launch_bounds__(256) void out_reduce2(
    const float* __restrict__ part2, const float* __restrict__ out_b,
    float* __restrict__ out)
{
    const int i = blockIdx.x * 256 + threadIdx.x;
    float s = 0.f;
    #pragma unroll
    for (int rr = 0; rr < 8; ++rr) s += part2[rr * 4096 + i];
    out[i] = out_b[i & (OUTN - 1)] + s;
}

// ---------------------------------------------------------------------------
extern "C" void kernel_launch(void* const* d_in, const int* in_sizes, int n_in,
                              void* d_out, int out_size, void* d_ws, size_t ws_size,
                              hipStream_t stream)
{
    const float* x          = (const float*)d_in[0];
    const float* prototypes = (const float*)d_in[1];
    const float* emb_w      = (const float*)d_in[2];
    const float* emb_b      = (const float*)d_in[3];
    const float* proj_w     = (const float*)d_in[4];
    const float* proj_b     = (const float*)d_in[5];
    const float* in_proj_w  = (const float*)d_in[6];
    const float* in_proj_b  = (const float*)d_in[7];
    const float* out_proj_w = (const float*)d_in[8];
    const float* out_proj_b = (const float*)d_in[9];
    const float* ln1_s      = (const float*)d_in[10];
    const float* ln1_b      = (const float*)d_in[11];
    const float* ffn_w1     = (const float*)d_in[12];
    const float* ffn_b1     = (const float*)d_in[13];
    const float* ffn_w2     = (const float*)d_in[14];
    const float* ffn_b2     = (const float*)d_in[15];
    const float* ln2_s      = (const float*)d_in[16];
    const float* ln2_b      = (const float*)d_in[17];
    const float* out_w      = (const float*)d_in[18];
    const float* out_b      = (const float*)d_in[19];
    float* out = (float*)d_out;
    char* base = (char*)d_ws;

    float*    seq    = (float*)base;                        // 12,582,912
    float*    tmp    = (float*)(base + 12582912);           // 12,582,912 (= part)
    ushort_t* seq_bf = (ushort_t*)(base + 25165824);        //  6,291,456
    ushort_t* qkv_bf = (ushort_t*)(base + 31457280);        // 18,874,368
    ushort_t* ctx_bf = (ushort_t*)(base + 50331648);        //  6,291,456
    ushort_t* w_bf   = (ushort_t*)(base + 56623104);        //    327,680
    float*    part   = tmp;                                 // 8 MB (written late)
    float*    part2  = (float*)(base + 12582912 + 8388608); // 128 KB
    float*    peT    = (float*)(base + 12582912 + 9437184); // 384 KB (written early,
    (void)ws_size;                                          //  reused later by nothing)

    ushort_t* w_in  = w_bf;            // [2][384][128]
    ushort_t* w_out = w_bf + 98304;    // [2][128][128]
    ushort_t* w_f1  = w_bf + 131072;   // [2][64][128]
    ushort_t* w_f2  = w_bf + 147456;   // [2][128][64]

    // 163840 cast elements + 98304 PE entries = 262144 = 1024 * 256
    cast_all_kernel<<<1024, 256, 0, stream>>>(
        in_proj_w, 98304, out_proj_w, 32768, ffn_w1, 16384, ffn_w2, 16384,
        w_in, w_out, w_f1, w_f2, peT);

    embed_kernel<<<ROWS, 128, 0, stream>>>(x, prototypes, emb_w, emb_b,
                                           proj_w, proj_b, peT, seq, seq_bf);

    for (int l = 0; l < 2; ++l) {
        // qkv = seq @ Wqkv^T + b -> bf16 [24576, 384], Q pre-scaled 0.25*log2e
        gemm_direct<<<dim3(6, 192), 256, 0, stream>>>(
            seq_bf, w_in + (size_t)l * 49152, in_proj_b + l * 384,
            qkv_bf, ROWS, 384, 128, 2 | 4);
        attention_mfma<<<dim3(BB * HH, 3), 512, 0, stream>>>(qkv_bf, ctx_bf);
        // seq = LN(seq + ctx @ Wout^T + b)
        gemm_ln_direct<<<ROWS / 64, 256, 0, stream>>>(
            ctx_bf, w_out + (size_t)l * 16384, out_proj_b + l * 128,
            ln1_s + l * EE, ln1_b + l * EE, seq, seq_bf, 128);
        // seq = LN(seq + elu(seq@W1^T+b1)@W2^T + b2)  (fully fused FFN)
        ffn_fused<<<ROWS / 64, 256, 0, stream>>>(
            seq_bf, w_f1 + (size_t)l * 8192, ffn_b1 + l * II,
            w_f2 + (size_t)l * 8192, ffn_b2 + l * EE,
            ln2_s + l * EE, ln2_b + l * EE, seq, seq_bf);
    }

    out_gemm3<<<PNBLK, 256, 0, stream>>>(seq_bf, out_w, part);
    out_reduce1<<<128, 256, 0, stream>>>(part, part2);
    out_reduce2<<<BB * OUTN / 256, 256, 0, stream>>>(part2, out_b, out);
}

// Round 2
// 296.966 us; speedup vs baseline: 1.1671x; 1.0662x over previous
//
#include <hip/hip_runtime.h>
#include <hip/hip_bf16.h>
#include <math.h>

typedef unsigned short ushort_t;
typedef unsigned int uint_t;

// Problem constants
#define BB 32
#define PP 6
#define DD 96
#define EE 128
#define HH 8
#define II 64
#define KK 32
#define LSEQ 768            // N*D
#define ROWS (BB * LSEQ)    // 24576 token rows
#define OUTN 128
#define KOUT (LSEQ * EE)    // 98304

using bf16x8 = __attribute__((ext_vector_type(8))) short;
using bf16x4 = __attribute__((ext_vector_type(4))) short;
using f32x4  = __attribute__((ext_vector_type(4))) float;
using u32x4  = __attribute__((ext_vector_type(4))) uint_t;

__device__ __forceinline__ ushort_t f2b(float f) {
    __hip_bfloat16 h = __float2bfloat16(f);
    return *reinterpret_cast<ushort_t*>(&h);
}
// pack two fp32 -> (bf16(hi)<<16)|bf16(lo) by TRUNCATION: one v_perm_b32.
__device__ __forceinline__ uint_t permpack(float hi, float lo) {
    return __builtin_amdgcn_perm(__builtin_bit_cast(uint_t, hi),
                                 __builtin_bit_cast(uint_t, lo), 0x07060302u);
}

// ---------------------------------------------------------------------------
// Cast fp32 -> bf16 (four weight tensors) + positional-encoding table.
// ---------------------------------------------------------------------------
__global__ void cast_all_kernel(
    const float* __restrict__ s0, int n0, const float* __restrict__ s1, int n1,
    const float* __restrict__ s2, int n2, const float* __restrict__ s3, int n3,
    ushort_t* __restrict__ d0, ushort_t* __restrict__ d1,
    ushort_t* __restrict__ d2, ushort_t* __restrict__ d3,
    float* __restrict__ peT)
{
    int i = blockIdx.x * 256 + threadIdx.x;
    if (i < n0) { d0[i] = f2b(s0[i]); return; }
    i -= n0;
    if (i < n1) { d1[i] = f2b(s1[i]); return; }
    i -= n1;
    if (i < n2) { d2[i] = f2b(s2[i]); return; }
    i -= n2;
    if (i < n3) { d3[i] = f2b(s3[i]); return; }
    i -= n3;
    // PE table: i in [0, LSEQ*EE)
    const int lpos = i >> 7, tt = i & 127;
    const float twoj = (float)((tt >> 1) * 2);
    const float div = __expf(twoj * (-9.210340371976184f / 128.0f));
    const float ang = (float)lpos * div;
    peT[i] = (tt & 1) ? __cosf(ang) : __sinf(ang);
}

// ---------------------------------------------------------------------------
// Embed: PE from precomputed table.
// ---------------------------------------------------------------------------
__global__ __launch_bounds__(128) void embed_kernel(
    const float* __restrict__ x, const float* __restrict__ prot,
    const float* __restrict__ emb_w, const float* __restrict__ emb_b,
    const float* __restrict__ proj_w, const float* __restrict__ proj_b,
    const float* __restrict__ peT,
    float* __restrict__ seq, ushort_t* __restrict__ seq_bf)
{
    const int r = blockIdx.x;
    const int t = threadIdx.x;
    __shared__ float xrow[PP];
    __shared__ float sel[PP];

    if (t < PP) xrow[t] = x[r * PP + t];
    __syncthreads();

    float nx = 0.f;
    #pragma unroll
    for (int p = 0; p < PP; ++p) nx += xrow[p] * xrow[p];
    const float xinv = 1.f / fmaxf(sqrtf(nx), 1e-12f);

    const int d = r % DD;
    if (t < KK) {
        const float* pr = prot + (d * KK + t) * PP;
        float pp[PP];
        float np2 = 0.f;
        #pragma unroll
        for (int p = 0; p < PP; ++p) { pp[p] = pr[p]; np2 += pp[p] * pp[p]; }
        const float pinv = 1.f / fmaxf(sqrtf(np2), 1e-12f);
        float dot = 0.f;
        #pragma unroll
        for (int p = 0; p < PP; ++p) dot += xrow[p] * pp[p];
        float sim = dot * xinv * pinv;
        int k = t;
        #pragma unroll
        for (int off = 16; off; off >>= 1) {
            float osim = __shfl_down(sim, off);
            int   ok   = __shfl_down(k, off);
            if (osim > sim || (osim == sim && ok < k)) { sim = osim; k = ok; }
        }
        k = __shfl(k, 0);
        if (t == k) {
            #pragma unroll
            for (int p = 0; p < PP; ++p) sel[p] = pp[p] * pinv;
        }
    }
    __syncthreads();

    float acc = emb_b[t] + proj_b[t];
    #pragma unroll
    for (int p = 0; p < PP; ++p) acc = fmaf(xrow[p], emb_w[t * PP + p], acc);
    #pragma unroll
    for (int p = 0; p < PP; ++p) acc = fmaf(sel[p], proj_w[t * PP + p], acc);

    const int lpos = r % LSEQ;
    const float v = acc + peT[lpos * EE + t];
    seq[(size_t)r * EE + t] = v;
    seq_bf[(size_t)r * EE + t] = f2b(v);
}

// ---------------------------------------------------------------------------
// QKV GEMM with attention-native output layouts.
// C = seq_bf @ Wqkv^T + b, N=384 fixed, K=128 fixed.
//   n in [0,128):   Q -> q_bf[row][128], pre-scaled by 0.25*log2e
//   n in [128,256): K -> k2[bh][c4=krow/16][dg=dim/4][r16=krow%16][4dims]
//   n in [256,384): V -> v2[bh][c4][d=dim][kk=krow%16]
// so attention's inner-loop loads are fully coalesced 512B wave-loads.
// Branch on n0 is block-uniform (n-blocks of 64 never straddle Q/K/V).
// ---------------------------------------------------------------------------
__global__ __launch_bounds__(256) void gemm_qkv(
    const ushort_t* __restrict__ A, const ushort_t* __restrict__ W,
    const float* __restrict__ bias,
    ushort_t* __restrict__ q_bf, ushort_t* __restrict__ k2,
    ushort_t* __restrict__ v2)
{
    __shared__ ushort_t Ws[64 * 136];   // kp = 136 (K=128)
    const int t = threadIdx.x;
    const int wave = t >> 6, lane = t & 63;
    const int quad = lane >> 4, l16 = lane & 15;
    const int m0 = blockIdx.y * 128, n0 = blockIdx.x * 64;

    for (int c = t; c < 64 * 16; c += 256) {
        int row = c >> 4, col = c & 15;
        *(bf16x8*)&Ws[row * 136 + col * 8] =
            *(const bf16x8*)&W[(size_t)(n0 + row) * 128 + col * 8];
    }
    __syncthreads();

    f32x4 acc[2][4];
    #pragma unroll
    for (int s = 0; s < 2; ++s)
        #pragma unroll
        for (int nt = 0; nt < 4; ++nt)
            acc[s][nt] = (f32x4){0.f, 0.f, 0.f, 0.f};

    const ushort_t* a0p = A + (size_t)(m0 + wave * 32 + l16) * 128 + quad * 8;
    const ushort_t* a1p = a0p + (size_t)16 * 128;
    const ushort_t* wp  = &Ws[l16 * 136 + quad * 8];

    #pragma unroll
    for (int k0 = 0; k0 < 128; k0 += 32) {
        bf16x8 a0 = *(const bf16x8*)(a0p + k0);
        bf16x8 a1 = *(const bf16x8*)(a1p + k0);
        #pragma unroll
        for (int nt = 0; nt < 4; ++nt) {
            bf16x8 wf = *(const bf16x8*)(wp + nt * 16 * 136 + k0);
            acc[0][nt] = __builtin_amdgcn_mfma_f32_16x16x32_bf16(wf, a0, acc[0][nt], 0, 0, 0);
            acc[1][nt] = __builtin_amdgcn_mfma_f32_16x16x32_bf16(wf, a1, acc[1][nt], 0, 0, 0);
        }
    }

    const int b = blockIdx.y / 6;            // 6 m-blocks per batch (768/128)
    #pragma unroll
    for (int s = 0; s < 2; ++s) {
        const int m = m0 + wave * 32 + s * 16 + l16;
        const int l = m - b * LSEQ;          // position within sequence
        const int c4 = l >> 4, r16 = l & 15;
        #pragma unroll
        for (int nt = 0; nt < 4; ++nt) {
            const int nb = n0 + nt * 16 + quad * 4;
            float4 b4 = *(const float4*)&bias[nb];
            float v[4];
            #pragma unroll
            for (int r = 0; r < 4; ++r)
                v[r] = acc[s][nt][r] + ((const float*)&b4)[r];

            if (n0 < 128) {
                // Q: pre-scale by 1/sqrt(16) * log2(e)
                #pragma unroll
                for (int r = 0; r < 4; ++r) v[r] *= 0.36067376022224085f;
                uint2 w2;
                w2.x = permpack(v[1], v[0]);
                w2.y = permpack(v[3], v[2]);
                *(uint2*)&q_bf[(size_t)m * EE + nb] = w2;
            } else if (n0 < 256) {
                const int h = ((n0 - 128) >> 4) + nt;   // dim-within-head = quad*4..+3
                uint2 w2;
                w2.x = permpack(v[1], v[0]);
                w2.y = permpack(v[3], v[2]);
                *(uint2*)&k2[((((size_t)(b * HH + h)) * 48 + c4) * 4 + quad) * 64 + r16 * 4] = w2;
            } else {
                const int h = ((n0 - 256) >> 4) + nt;
                const size_t vbase = (((size_t)(b * HH + h)) * 48 + c4) * 16;
                #pragma unroll
                for (int r = 0; r < 4; ++r)
                    v2[(vbase + quad * 4 + r) * 16 + r16] = f2b(v[r]);
            }
        }
    }
}

// ---------------------------------------------------------------------------
// MFMA flash attention v7: zero LDS, zero barriers, coalesced operands.
// K/V read from attention-native layouts written by gemm_qkv: every inner
// loop load is one contiguous 512B wave-load (chunk stride 256 elems).
// 256 threads = 4 waves x 32 q; grid (256 bh, 6 qb) = 1536 blocks = 6/CU.
// 2-deep register prefetch; row-sum via ones-MFMA as in v6.
// ---------------------------------------------------------------------------
__global__ __launch_bounds__(256) void attention_mfma(
    const ushort_t* __restrict__ q_bf, const ushort_t* __restrict__ k2,
    const ushort_t* __restrict__ v2, ushort_t* __restrict__ ctx)
{
    const int bh = blockIdx.x;
    const int b = bh & 31, h = bh >> 5;     // XCD swizzle: id%8 == b%8
    const int qb = blockIdx.y;              // 0..5, 128 q each
    const int t = threadIdx.x;
    const int wave = t >> 6, lane = t & 63;
    const int quad = lane >> 4, l16 = lane & 15;
    const int hoff = h * 16;

    // Q fragments (one-time gather)
    bf16x4 qf[2];
    #pragma unroll
    for (int s = 0; s < 2; ++s) {
        int row = b * LSEQ + qb * 128 + wave * 32 + s * 16 + l16;
        qf[s] = *(const bf16x4*)&q_bf[(size_t)row * EE + hoff + quad * 4];
    }

    const int bhn = b * HH + h;
    const ushort_t* kp = k2 + (size_t)bhn * 12288 + quad * 64 + l16 * 4;
    const ushort_t* vp = v2 + (size_t)bhn * 12288 + l16 * 16 + quad * 4;

    f32x4 oacc[2], lacc[2];
    oacc[0] = (f32x4){0.f, 0.f, 0.f, 0.f};
    oacc[1] = (f32x4){0.f, 0.f, 0.f, 0.f};
    lacc[0] = (f32x4){0.f, 0.f, 0.f, 0.f};
    lacc[1] = (f32x4){0.f, 0.f, 0.f, 0.f};
    const f32x4 zero4 = (f32x4){0.f, 0.f, 0.f, 0.f};
    bf16x4 ones4;
    #pragma unroll
    for (int j = 0; j < 4; ++j) ones4[j] = (short)0x3F80;   // bf16 1.0

    bf16x4 kA = *(const bf16x4*)(kp);
    bf16x4 vA = *(const bf16x4*)(vp);
    bf16x4 kB = *(const bf16x4*)(kp + 256);
    bf16x4 vB = *(const bf16x4*)(vp + 256);

    for (int c4 = 0; c4 < 48; ++c4) {
        const int c4n = c4 < 46 ? c4 + 2 : 0;      // uniform, branchless
        bf16x4 kC = *(const bf16x4*)(kp + c4n * 256);
        bf16x4 vC = *(const bf16x4*)(vp + c4n * 256);

        #pragma unroll
        for (int s = 0; s < 2; ++s) {
            f32x4 sv = __builtin_amdgcn_mfma_f32_16x16x16bf16_1k(kA, qf[s], zero4, 0, 0, 0);
            float e0 = __builtin_amdgcn_exp2f(sv[0]);
            float e1 = __builtin_amdgcn_exp2f(sv[1]);
            float e2 = __builtin_amdgcn_exp2f(sv[2]);
            float e3 = __builtin_amdgcn_exp2f(sv[3]);
            uint2 pu;
            pu.x = permpack(e1, e0);
            pu.y = permpack(e3, e2);
            bf16x4 pf = __builtin_bit_cast(bf16x4, pu);
            oacc[s] = __builtin_amdgcn_mfma_f32_16x16x16bf16_1k(vA, pf, oacc[s], 0, 0, 0);
            lacc[s] = __builtin_amdgcn_mfma_f32_16x16x16bf16_1k(ones4, pf, lacc[s], 0, 0, 0);
        }
        kA = kB; vA = vB; kB = kC; vB = vC;
    }

    #pragma unroll
    for (int s = 0; s < 2; ++s) {
        const float inv = 1.f / lacc[s][0];     // row-replicated full sum
        const int q = qb * 128 + wave * 32 + s * 16 + l16;
        uint2 w2;
        w2.x = permpack(oacc[s][1] * inv, oacc[s][0] * inv);
        w2.y = permpack(oacc[s][3] * inv, oacc[s][2] * inv);
        *(uint2*)&ctx[((size_t)(b * LSEQ + q)) * EE + hoff + quad * 4] = w2;
    }
}

// ---------------------------------------------------------------------------
// Direct-activation GEMM + residual + LayerNorm (N=128). (unchanged)
// ---------------------------------------------------------------------------
__global__ __launch_bounds__(256) void gemm_ln_direct(
    const ushort_t* __restrict__ A, const ushort_t* __restrict__ W,
    const float* __restrict__ bias,
    const float* __restrict__ gamma, const float* __restrict__ beta,
    float* __restrict__ seq, ushort_t* __restrict__ seq_bf, int K)
{
    __shared__ ushort_t Ws[128 * 136];
    const int t = threadIdx.x;
    const int wave = t >> 6, lane = t & 63;
    const int quad = lane >> 4, l16 = lane & 15;
    const int m0 = blockIdx.x * 64;
    const int kp = K + 8;
    const int ak8 = K >> 3;

    for (int c = t; c < 128 * ak8; c += 256) {
        int row = c / ak8, col = c - row * ak8;
        *(bf16x8*)&Ws[row * kp + col * 8] =
            *(const bf16x8*)&W[(size_t)row * K + col * 8];
    }
    __syncthreads();

    f32x4 acc[8];
    #pragma unroll
    for (int nt = 0; nt < 8; ++nt) acc[nt] = (f32x4){0.f, 0.f, 0.f, 0.f};

    const int m = m0 + wave * 16 + l16;
    const ushort_t* ap = A + (size_t)m * K + quad * 8;
    const ushort_t* wp = &Ws[l16 * kp + quad * 8];

    for (int k0 = 0; k0 < K; k0 += 32) {
        bf16x8 a = *(const bf16x8*)(ap + k0);
        #pragma unroll
        for (int nt = 0; nt < 8; ++nt) {
            bf16x8 wf = *(const bf16x8*)(wp + nt * 16 * kp + k0);
            acc[nt] = __builtin_amdgcn_mfma_f32_16x16x32_bf16(wf, a, acc[nt], 0, 0, 0);
        }
    }

    float v[8][4];
    float s = 0.f;
    #pragma unroll
    for (int nt = 0; nt < 8; ++nt) {
        const int nb = nt * 16 + quad * 4;
        float4 b4 = *(const float4*)&bias[nb];
        float4 r4 = *(const float4*)&seq[(size_t)m * EE + nb];
        #pragma unroll
        for (int r = 0; r < 4; ++r) {
            v[nt][r] = acc[nt][r] + ((const float*)&b4)[r] + ((const float*)&r4)[r];
            s += v[nt][r];
        }
    }
    s += __shfl_xor(s, 16);
    s += __shfl_xor(s, 32);
    const float mean = s * (1.f / 128.f);
    float s2 = 0.f;
    #pragma unroll
    for (int nt = 0; nt < 8; ++nt)
        #pragma unroll
        for (int r = 0; r < 4; ++r) {
            float d = v[nt][r] - mean;
            s2 += d * d;
        }
    s2 += __shfl_xor(s2, 16);
    s2 += __shfl_xor(s2, 32);
    const float rstd = 1.f / sqrtf(s2 * (1.f / 128.f) + 1e-5f);

    #pragma unroll
    for (int nt = 0; nt < 8; ++nt) {
        const int nb = nt * 16 + quad * 4;
        float4 g4 = *(const float4*)&gamma[nb];
        float4 be4 = *(const float4*)&beta[nb];
        float y[4];
        #pragma unroll
        for (int r = 0; r < 4; ++r)
            y[r] = (v[nt][r] - mean) * rstd * ((const float*)&g4)[r] + ((const float*)&be4)[r];
        float4 f4 = {y[0], y[1], y[2], y[3]};
        *(float4*)&seq[(size_t)m * EE + nb] = f4;
        uint2 w2;
        w2.x = permpack(y[1], y[0]);
        w2.y = permpack(y[3], y[2]);
        *(uint2*)&seq_bf[(size_t)m * EE + nb] = w2;
    }
}

// ---------------------------------------------------------------------------
// Fused FFN (unchanged).
// ---------------------------------------------------------------------------
__global__ __launch_bounds__(256) void ffn_fused(
    const ushort_t* __restrict__ seq_bf_in, const ushort_t* __restrict__ W1,
    const float* __restrict__ b1, const ushort_t* __restrict__ W2,
    const float* __restrict__ b2,
    const float* __restrict__ gamma, const float* __restrict__ beta,
    float* __restrict__ seq, ushort_t* __restrict__ seq_bf)
{
    __shared__ ushort_t W1s[64 * 136];
    __shared__ ushort_t W2s[128 * 72];
    __shared__ ushort_t Hs[64 * 72];
    const int t = threadIdx.x;
    const int wave = t >> 6, lane = t & 63;
    const int quad = lane >> 4, l16 = lane & 15;
    const int m0 = blockIdx.x * 64;

    for (int c = t; c < 64 * 16; c += 256) {
        int row = c >> 4, col = c & 15;
        *(bf16x8*)&W1s[row * 136 + col * 8] =
            *(const bf16x8*)&W1[(size_t)row * 128 + col * 8];
    }
    for (int c = t; c < 128 * 8; c += 256) {
        int row = c >> 3, col = c & 7;
        *(bf16x8*)&W2s[row * 72 + col * 8] =
            *(const bf16x8*)&W2[(size_t)row * 64 + col * 8];
    }
    __syncthreads();

    const int lrow = wave * 16 + l16;
    const int m = m0 + lrow;
    f32x4 acc1[4];
    #pragma unroll
    for (int nt = 0; nt < 4; ++nt) acc1[nt] = (f32x4){0.f, 0.f, 0.f, 0.f};

    const ushort_t* ap = seq_bf_in + (size_t)m * EE + quad * 8;
    const ushort_t* w1p = &W1s[l16 * 136 + quad * 8];
    for (int k0 = 0; k0 < 128; k0 += 32) {
        bf16x8 a = *(const bf16x8*)(ap + k0);
        #pragma unroll
        for (int nt = 0; nt < 4; ++nt) {
            bf16x8 wf = *(const bf16x8*)(w1p + nt * 16 * 136 + k0);
            acc1[nt] = __builtin_amdgcn_mfma_f32_16x16x32_bf16(wf, a, acc1[nt], 0, 0, 0);
        }
    }
    #pragma unroll
    for (int nt = 0; nt < 4; ++nt) {
        const int ib = nt * 16 + quad * 4;
        float4 b4 = *(const float4*)&b1[ib];
        float hv[4];
        #pragma unroll
        for (int r = 0; r < 4; ++r) {
            float u = acc1[nt][r] + ((const float*)&b4)[r];
            hv[r] = u > 0.f ? u : expm1f(u);
        }
        uint2 w2;
        w2.x = permpack(hv[1], hv[0]);
        w2.y = permpack(hv[3], hv[2]);
        *(uint2*)&Hs[lrow * 72 + ib] = w2;
    }

    f32x4 acc2[8];
    #pragma unroll
    for (int nt = 0; nt < 8; ++nt) acc2[nt] = (f32x4){0.f, 0.f, 0.f, 0.f};
    const ushort_t* hp = &Hs[lrow * 72 + quad * 8];
    const ushort_t* w2p = &W2s[l16 * 72 + quad * 8];
    #pragma unroll
    for (int k0 = 0; k0 < 64; k0 += 32) {
        bf16x8 hf = *(const bf16x8*)(hp + k0);
        #pragma unroll
        for (int nt = 0; nt < 8; ++nt) {
            bf16x8 wf = *(const bf16x8*)(w2p + nt * 16 * 72 + k0);
            acc2[nt] = __builtin_amdgcn_mfma_f32_16x16x32_bf16(wf, hf, acc2[nt], 0, 0, 0);
        }
    }

    float v[8][4];
    float s = 0.f;
    #pragma unroll
    for (int nt = 0; nt < 8; ++nt) {
        const int nb = nt * 16 + quad * 4;
        float4 b4 = *(const float4*)&b2[nb];
        float4 r4 = *(const float4*)&seq[(size_t)m * EE + nb];
        #pragma unroll
        for (int r = 0; r < 4; ++r) {
            v[nt][r] = acc2[nt][r] + ((const float*)&b4)[r] + ((const float*)&r4)[r];
            s += v[nt][r];
        }
    }
    s += __shfl_xor(s, 16);
    s += __shfl_xor(s, 32);
    const float mean = s * (1.f / 128.f);
    float s2 = 0.f;
    #pragma unroll
    for (int nt = 0; nt < 8; ++nt)
        #pragma unroll
        for (int r = 0; r < 4; ++r) {
            float d = v[nt][r] - mean;
            s2 += d * d;
        }
    s2 += __shfl_xor(s2, 16);
    s2 += __shfl_xor(s2, 32);
    const float rstd = 1.f / sqrtf(s2 * (1.f / 128.f) + 1e-5f);

    #pragma unroll
    for (int nt = 0; nt < 8; ++nt) {
        const int nb = nt * 16 + quad * 4;
        float4 g4 = *(const float4*)&gamma[nb];
        float4 be4 = *(const float4*)&beta[nb];
        float y[4];
        #pragma unroll
        for (int r = 0; r < 4; ++r)
            y[r] = (v[nt][r] - mean) * rstd * ((const float*)&g4)[r] + ((const float*)&be4)[r];
        float4 f4 = {y[0], y[1], y[2], y[3]};
        *(float4*)&seq[(size_t)m * EE + nb] = f4;
        uint2 w2;
        w2.x = permpack(y[1], y[0]);
        w2.y = permpack(y[3], y[2]);
        *(uint2*)&seq_bf[(size_t)m * EE + nb] = w2;
    }
}

// ---------------------------------------------------------------------------
// Final projection, split-K MFMA (unchanged).
// ---------------------------------------------------------------------------
#define PKC 192
#define PNBLK (KOUT / PKC)   // 512
__global__ __launch_bounds__(256) void out_gemm3(
    const ushort_t* __restrict__ seqbf, const float* __restrict__ out_w,
    float* __restrict__ part)
{
    const int t = threadIdx.x;
    const int wave = t >> 6, lane = t & 63;
    const int quad = lane >> 4, l16 = lane & 15;
    const size_t k0 = (size_t)blockIdx.x * PKC;
    const int n0 = wave * 32;

    f32x4 acc[2][2];
    #pragma unroll
    for (int mt = 0; mt < 2; ++mt)
        #pragma unroll
        for (int nt = 0; nt < 2; ++nt)
            acc[mt][nt] = (f32x4){0.f, 0.f, 0.f, 0.f};

    const ushort_t* a0p = seqbf + (size_t)l16 * KOUT + k0 + quad * 8;
    const ushort_t* a1p = a0p + (size_t)16 * KOUT;
    const float* w0p = out_w + (size_t)(n0 + l16) * KOUT + k0 + quad * 8;
    const float* w1p = w0p + (size_t)16 * KOUT;

    #pragma unroll
    for (int ks = 0; ks < PKC; ks += 32) {
        bf16x8 a0 = *(const bf16x8*)(a0p + ks);
        bf16x8 a1 = *(const bf16x8*)(a1p + ks);
        float4 wa0 = *(const float4*)(w0p + ks);
        float4 wa1 = *(const float4*)(w0p + ks + 4);
        float4 wb0 = *(const float4*)(w1p + ks);
        float4 wb1 = *(const float4*)(w1p + ks + 4);
        u32x4 b0, b1;
        b0[0] = permpack(wa0.y, wa0.x); b0[1] = permpack(wa0.w, wa0.z);
        b0[2] = permpack(wa1.y, wa1.x); b0[3] = permpack(wa1.w, wa1.z);
        b1[0] = permpack(wb0.y, wb0.x); b1[1] = permpack(wb0.w, wb0.z);
        b1[2] = permpack(wb1.y, wb1.x); b1[3] = permpack(wb1.w, wb1.z);
        bf16x8 bf0 = __builtin_bit_cast(bf16x8, b0);
        bf16x8 bf1 = __builtin_bit_cast(bf16x8, b1);
        acc[0][0] = __builtin_amdgcn_mfma_f32_16x16x32_bf16(a0, bf0, acc[0][0], 0, 0, 0);
        acc[1][0] = __builtin_amdgcn_mfma_f32_16x16x32_bf16(a1, bf0, acc[1][0], 0, 0, 0);
        acc[0][1] = __builtin_amdgcn_mfma_f32_16x16x32_bf16(a0, bf1, acc[0][1], 0, 0, 0);
        acc[1][1] = __builtin_amdgcn_mfma_f32_16x16x32_bf16(a1, bf1, acc[1][1], 0, 0, 0);
    }

    float* pb = part + (size_t)blockIdx.x * (32 * 128);
    #pragma unroll
    for (int mt = 0; mt < 2; ++mt)
        #pragma unroll
        for (int nt = 0; nt < 2; ++nt)
            #pragma unroll
            for (int r = 0; r < 4; ++r)
                pb[(mt * 16 + quad * 4 + r) * 128 + n0 + nt * 16 + l16] = acc[mt][nt][r];
}

// ---------------------------------------------------------------------------
// Two-stage partial reduction (unchanged).
// ---------------------------------------------------------------------------
__global__ __launch_bounds__(256) void out_reduce1(
    const float* __restrict__ part, float* __restrict__ part2)
{
    const int g = blockIdx.x & 15, rr = blockIdx.x >> 4;   // rr in 0..7
    const int i = g * 256 + threadIdx.x;
    const float* p = part + (size_t)rr * 64 * 4096 + i;
    float s0 = 0.f, s1 = 0.f, s2 = 0.f, s3 = 0.f;
    for (int blk = 0; blk < 64; blk += 4) {
        s0 += p[(size_t)blk * 4096];
        s1 += p[(size_t)(blk + 1) * 4096];
        s2 += p[(size_t)(blk + 2) * 4096];
        s3 += p[(size_t)(blk + 3) * 4096];
    }
    part2[rr * 4096 + i] = (s0 + s1) + (s2 + s3);
}

__global__ __launch_bounds__(256) void out_reduce2(
    const float* __restrict__ part2, const float* __restrict__ out_b,
    float* __restrict__ out)
{
    const int i = blockIdx.x * 256 + threadIdx.x;
    float s = 0.f;
    #pragma unroll
    for (int rr = 0; rr < 8; ++rr) s += part2[rr * 4096 + i];
    out[i] = out_b[i & (OUTN - 1)] + s;
}

// ---------------------------------------------------------------------------
extern "C" void kernel_launch(void* const* d_in, const int* in_sizes, int n_in,
                              void* d_out, int out_size, void* d_ws, size_t ws_size,
                              hipStream_t stream)
{
    const float* x          = (const float*)d_in[0];
    const float* prototypes = (const float*)d_in[1];
    const float* emb_w      = (const float*)d_in[2];
    const float* emb_b      = (const float*)d_in[3];
    const float* proj_w     = (const float*)d_in[4];
    const float* proj_b     = (const float*)d_in[5];
    const float* in_proj_w  = (const float*)d_in[6];
    const float* in_proj_b  = (const float*)d_in[7];
    const float* out_proj_w = (const float*)d_in[8];
    const float* out_proj_b = (const float*)d_in[9];
    const float* ln1_s      = (const float*)d_in[10];
    const float* ln1_b      = (const float*)d_in[11];
    const float* ffn_w1     = (const float*)d_in[12];
    const float* ffn_b1     = (const float*)d_in[13];
    const float* ffn_w2     = (const float*)d_in[14];
    const float* ffn_b2     = (const float*)d_in[15];
    const float* ln2_s      = (const float*)d_in[16];
    const float* ln2_b      = (const float*)d_in[17];
    const float* out_w      = (const float*)d_in[18];
    const float* out_b      = (const float*)d_in[19];
    float* out = (float*)d_out;
    char* base = (char*)d_ws;

    float*    seq    = (float*)base;                        // 12,582,912
    float*    tmp    = (float*)(base + 12582912);           // 12,582,912 (= part)
    ushort_t* seq_bf = (ushort_t*)(base + 25165824);        //  6,291,456
    ushort_t* q_bf   = (ushort_t*)(base + 31457280);        //  6,291,456
    ushort_t* k2     = (ushort_t*)(base + 37748736);        //  6,291,456
    ushort_t* v2     = (ushort_t*)(base + 44040192);        //  6,291,456
    ushort_t* ctx_bf = (ushort_t*)(base + 50331648);        //  6,291,456
    ushort_t* w_bf   = (ushort_t*)(base + 56623104);        //    327,680
    float*    part   = tmp;                                 // 8 MB (written late)
    float*    part2  = (float*)(base + 12582912 + 8388608); // 128 KB
    float*    peT    = (float*)(base + 12582912 + 9437184); // 384 KB
    (void)ws_size;

    ushort_t* w_in  = w_bf;            // [2][384][128]
    ushort_t* w_out = w_bf + 98304;    // [2][128][128]
    ushort_t* w_f1  = w_bf + 131072;   // [2][64][128]
    ushort_t* w_f2  = w_bf + 147456;   // [2][128][64]

    // 163840 cast elements + 98304 PE entries = 262144 = 1024 * 256
    cast_all_kernel<<<1024, 256, 0, stream>>>(
        in_proj_w, 98304, out_proj_w, 32768, ffn_w1, 16384, ffn_w2, 16384,
        w_in, w_out, w_f1, w_f2, peT);

    embed_kernel<<<ROWS, 128, 0, stream>>>(x, prototypes, emb_w, emb_b,
                                           proj_w, proj_b, peT, seq, seq_bf);

    for (int l = 0; l < 2; ++l) {
        // qkv = seq @ Wqkv^T + b -> Q[row][128] (pre-scaled), K/V in
        // attention-native layouts.
        gemm_qkv<<<dim3(6, 192), 256, 0, stream>>>(
            seq_bf, w_in + (size_t)l * 49152, in_proj_b + l * 384,
            q_bf, k2, v2);
        attention_mfma<<<dim3(BB * HH, 6), 256, 0, stream>>>(q_bf, k2, v2, ctx_bf);
        // seq = LN(seq + ctx @ Wout^T + b)
        gemm_ln_direct<<<ROWS / 64, 256, 0, stream>>>(
            ctx_bf, w_out + (size_t)l * 16384, out_proj_b + l * 128,
            ln1_s + l * EE, ln1_b + l * EE, seq, seq_bf, 128);
        // seq = LN(seq + elu(seq@W1^T+b1)@W2^T + b2)  (fully fused FFN)
        ffn_fused<<<ROWS / 64, 256, 0, stream>>>(
            seq_bf, w_f1 + (size_t)l * 8192, ffn_b1 + l * II,
            w_f2 + (size_t)l * 8192, ffn_b2 + l * EE,
            ln2_s + l * EE, ln2_b + l * EE, seq, seq_bf);
    }

    out_gemm3<<<PNBLK, 256, 0, stream>>>(seq_bf, out_w, part);
    out_reduce1<<<128, 256, 0, stream>>>(part, part2);
    out_reduce2<<<BB * OUTN / 256, 256, 0, stream>>>(part2, out_b, out);
}

// Round 3
// 282.433 us; speedup vs baseline: 1.2271x; 1.0515x over previous
//
#include <hip/hip_runtime.h>
#include <hip/hip_bf16.h>
#include <math.h>

typedef unsigned short ushort_t;
typedef unsigned int uint_t;

// Problem constants
#define BB 32
#define PP 6
#define DD 96
#define EE 128
#define HH 8
#define II 64
#define KK 32
#define LSEQ 768            // N*D
#define ROWS (BB * LSEQ)    // 24576 token rows
#define OUTN 128
#define KOUT (LSEQ * EE)    // 98304

using bf16x8 = __attribute__((ext_vector_type(8))) short;
using bf16x4 = __attribute__((ext_vector_type(4))) short;
using f32x4  = __attribute__((ext_vector_type(4))) float;
using u32x4  = __attribute__((ext_vector_type(4))) uint_t;

__device__ __forceinline__ ushort_t f2b(float f) {
    __hip_bfloat16 h = __float2bfloat16(f);
    return *reinterpret_cast<ushort_t*>(&h);
}
// pack two fp32 -> (bf16(hi)<<16)|bf16(lo) by TRUNCATION: one v_perm_b32.
__device__ __forceinline__ uint_t permpack(float hi, float lo) {
    return __builtin_amdgcn_perm(__builtin_bit_cast(uint_t, hi),
                                 __builtin_bit_cast(uint_t, lo), 0x07060302u);
}

// ---------------------------------------------------------------------------
// Cast fp32 -> bf16 (four weight tensors) + positional-encoding table.
// ---------------------------------------------------------------------------
__global__ void cast_all_kernel(
    const float* __restrict__ s0, int n0, const float* __restrict__ s1, int n1,
    const float* __restrict__ s2, int n2, const float* __restrict__ s3, int n3,
    ushort_t* __restrict__ d0, ushort_t* __restrict__ d1,
    ushort_t* __restrict__ d2, ushort_t* __restrict__ d3,
    float* __restrict__ peT)
{
    int i = blockIdx.x * 256 + threadIdx.x;
    if (i < n0) { d0[i] = f2b(s0[i]); return; }
    i -= n0;
    if (i < n1) { d1[i] = f2b(s1[i]); return; }
    i -= n1;
    if (i < n2) { d2[i] = f2b(s2[i]); return; }
    i -= n2;
    if (i < n3) { d3[i] = f2b(s3[i]); return; }
    i -= n3;
    // PE table: i in [0, LSEQ*EE)
    const int lpos = i >> 7, tt = i & 127;
    const float twoj = (float)((tt >> 1) * 2);
    const float div = __expf(twoj * (-9.210340371976184f / 128.0f));
    const float ang = (float)lpos * div;
    peT[i] = (tt & 1) ? __cosf(ang) : __sinf(ang);
}

// ---------------------------------------------------------------------------
// Embed: PE from precomputed table.
// ---------------------------------------------------------------------------
__global__ __launch_bounds__(128) void embed_kernel(
    const float* __restrict__ x, const float* __restrict__ prot,
    const float* __restrict__ emb_w, const float* __restrict__ emb_b,
    const float* __restrict__ proj_w, const float* __restrict__ proj_b,
    const float* __restrict__ peT,
    float* __restrict__ seq, ushort_t* __restrict__ seq_bf)
{
    const int r = blockIdx.x;
    const int t = threadIdx.x;
    __shared__ float xrow[PP];
    __shared__ float sel[PP];

    if (t < PP) xrow[t] = x[r * PP + t];
    __syncthreads();

    float nx = 0.f;
    #pragma unroll
    for (int p = 0; p < PP; ++p) nx += xrow[p] * xrow[p];
    const float xinv = 1.f / fmaxf(sqrtf(nx), 1e-12f);

    const int d = r % DD;
    if (t < KK) {
        const float* pr = prot + (d * KK + t) * PP;
        float pp[PP];
        float np2 = 0.f;
        #pragma unroll
        for (int p = 0; p < PP; ++p) { pp[p] = pr[p]; np2 += pp[p] * pp[p]; }
        const float pinv = 1.f / fmaxf(sqrtf(np2), 1e-12f);
        float dot = 0.f;
        #pragma unroll
        for (int p = 0; p < PP; ++p) dot += xrow[p] * pp[p];
        float sim = dot * xinv * pinv;
        int k = t;
        #pragma unroll
        for (int off = 16; off; off >>= 1) {
            float osim = __shfl_down(sim, off);
            int   ok   = __shfl_down(k, off);
            if (osim > sim || (osim == sim && ok < k)) { sim = osim; k = ok; }
        }
        k = __shfl(k, 0);
        if (t == k) {
            #pragma unroll
            for (int p = 0; p < PP; ++p) sel[p] = pp[p] * pinv;
        }
    }
    __syncthreads();

    float acc = emb_b[t] + proj_b[t];
    #pragma unroll
    for (int p = 0; p < PP; ++p) acc = fmaf(xrow[p], emb_w[t * PP + p], acc);
    #pragma unroll
    for (int p = 0; p < PP; ++p) acc = fmaf(sel[p], proj_w[t * PP + p], acc);

    const int lpos = r % LSEQ;
    const float v = acc + peT[lpos * EE + t];
    seq[(size_t)r * EE + t] = v;
    seq_bf[(size_t)r * EE + t] = f2b(v);
}

// ---------------------------------------------------------------------------
// QKV GEMM with attention-native output layouts (unchanged from round 2).
// ---------------------------------------------------------------------------
__global__ __launch_bounds__(256) void gemm_qkv(
    const ushort_t* __restrict__ A, const ushort_t* __restrict__ W,
    const float* __restrict__ bias,
    ushort_t* __restrict__ q_bf, ushort_t* __restrict__ k2,
    ushort_t* __restrict__ v2)
{
    __shared__ ushort_t Ws[64 * 136];   // kp = 136 (K=128)
    const int t = threadIdx.x;
    const int wave = t >> 6, lane = t & 63;
    const int quad = lane >> 4, l16 = lane & 15;
    const int m0 = blockIdx.y * 128, n0 = blockIdx.x * 64;

    for (int c = t; c < 64 * 16; c += 256) {
        int row = c >> 4, col = c & 15;
        *(bf16x8*)&Ws[row * 136 + col * 8] =
            *(const bf16x8*)&W[(size_t)(n0 + row) * 128 + col * 8];
    }
    __syncthreads();

    f32x4 acc[2][4];
    #pragma unroll
    for (int s = 0; s < 2; ++s)
        #pragma unroll
        for (int nt = 0; nt < 4; ++nt)
            acc[s][nt] = (f32x4){0.f, 0.f, 0.f, 0.f};

    const ushort_t* a0p = A + (size_t)(m0 + wave * 32 + l16) * 128 + quad * 8;
    const ushort_t* a1p = a0p + (size_t)16 * 128;
    const ushort_t* wp  = &Ws[l16 * 136 + quad * 8];

    #pragma unroll
    for (int k0 = 0; k0 < 128; k0 += 32) {
        bf16x8 a0 = *(const bf16x8*)(a0p + k0);
        bf16x8 a1 = *(const bf16x8*)(a1p + k0);
        #pragma unroll
        for (int nt = 0; nt < 4; ++nt) {
            bf16x8 wf = *(const bf16x8*)(wp + nt * 16 * 136 + k0);
            acc[0][nt] = __builtin_amdgcn_mfma_f32_16x16x32_bf16(wf, a0, acc[0][nt], 0, 0, 0);
            acc[1][nt] = __builtin_amdgcn_mfma_f32_16x16x32_bf16(wf, a1, acc[1][nt], 0, 0, 0);
        }
    }

    const int b = blockIdx.y / 6;            // 6 m-blocks per batch (768/128)
    #pragma unroll
    for (int s = 0; s < 2; ++s) {
        const int m = m0 + wave * 32 + s * 16 + l16;
        const int l = m - b * LSEQ;          // position within sequence
        const int c4 = l >> 4, r16 = l & 15;
        #pragma unroll
        for (int nt = 0; nt < 4; ++nt) {
            const int nb = n0 + nt * 16 + quad * 4;
            float4 b4 = *(const float4*)&bias[nb];
            float v[4];
            #pragma unroll
            for (int r = 0; r < 4; ++r)
                v[r] = acc[s][nt][r] + ((const float*)&b4)[r];

            if (n0 < 128) {
                // Q: pre-scale by 1/sqrt(16) * log2(e)
                #pragma unroll
                for (int r = 0; r < 4; ++r) v[r] *= 0.36067376022224085f;
                uint2 w2;
                w2.x = permpack(v[1], v[0]);
                w2.y = permpack(v[3], v[2]);
                *(uint2*)&q_bf[(size_t)m * EE + nb] = w2;
            } else if (n0 < 256) {
                const int h = ((n0 - 128) >> 4) + nt;
                uint2 w2;
                w2.x = permpack(v[1], v[0]);
                w2.y = permpack(v[3], v[2]);
                *(uint2*)&k2[((((size_t)(b * HH + h)) * 48 + c4) * 4 + quad) * 64 + r16 * 4] = w2;
            } else {
                const int h = ((n0 - 256) >> 4) + nt;
                const size_t vbase = (((size_t)(b * HH + h)) * 48 + c4) * 16;
                #pragma unroll
                for (int r = 0; r < 4; ++r)
                    v2[(vbase + quad * 4 + r) * 16 + r16] = f2b(v[r]);
            }
        }
    }
}

// ---------------------------------------------------------------------------
// MFMA flash attention v8: 4-deep K/V register pipeline (was 2-deep).
// Load->use distance = 4 chunks (~8 dependent step-chains) > L2 latency.
// ---------------------------------------------------------------------------
__device__ __forceinline__ void attn_step(
    bf16x4 kf, bf16x4 vf, const bf16x4 (&qf)[2],
    f32x4 (&oacc)[2], f32x4 (&lacc)[2], bf16x4 ones4)
{
    const f32x4 zero4 = (f32x4){0.f, 0.f, 0.f, 0.f};
    #pragma unroll
    for (int s = 0; s < 2; ++s) {
        f32x4 sv = __builtin_amdgcn_mfma_f32_16x16x16bf16_1k(kf, qf[s], zero4, 0, 0, 0);
        float e0 = __builtin_amdgcn_exp2f(sv[0]);
        float e1 = __builtin_amdgcn_exp2f(sv[1]);
        float e2 = __builtin_amdgcn_exp2f(sv[2]);
        float e3 = __builtin_amdgcn_exp2f(sv[3]);
        uint2 pu;
        pu.x = permpack(e1, e0);
        pu.y = permpack(e3, e2);
        bf16x4 pf = __builtin_bit_cast(bf16x4, pu);
        oacc[s] = __builtin_amdgcn_mfma_f32_16x16x16bf16_1k(vf, pf, oacc[s], 0, 0, 0);
        lacc[s] = __builtin_amdgcn_mfma_f32_16x16x16bf16_1k(ones4, pf, lacc[s], 0, 0, 0);
    }
}

__global__ __launch_bounds__(256) void attention_mfma(
    const ushort_t* __restrict__ q_bf, const ushort_t* __restrict__ k2,
    const ushort_t* __restrict__ v2, ushort_t* __restrict__ ctx)
{
    const int bh = blockIdx.x;
    const int b = bh & 31, h = bh >> 5;     // XCD swizzle: id%8 == b%8
    const int qb = blockIdx.y;              // 0..5, 128 q each
    const int t = threadIdx.x;
    const int wave = t >> 6, lane = t & 63;
    const int quad = lane >> 4, l16 = lane & 15;
    const int hoff = h * 16;

    // Q fragments (one-time gather)
    bf16x4 qf[2];
    #pragma unroll
    for (int s = 0; s < 2; ++s) {
        int row = b * LSEQ + qb * 128 + wave * 32 + s * 16 + l16;
        qf[s] = *(const bf16x4*)&q_bf[(size_t)row * EE + hoff + quad * 4];
    }

    const int bhn = b * HH + h;
    const ushort_t* kp = k2 + (size_t)bhn * 12288 + quad * 64 + l16 * 4;
    const ushort_t* vp = v2 + (size_t)bhn * 12288 + l16 * 16 + quad * 4;

    f32x4 oacc[2], lacc[2];
    oacc[0] = (f32x4){0.f, 0.f, 0.f, 0.f};
    oacc[1] = (f32x4){0.f, 0.f, 0.f, 0.f};
    lacc[0] = (f32x4){0.f, 0.f, 0.f, 0.f};
    lacc[1] = (f32x4){0.f, 0.f, 0.f, 0.f};
    bf16x4 ones4;
    #pragma unroll
    for (int j = 0; j < 4; ++j) ones4[j] = (short)0x3F80;   // bf16 1.0

    bf16x4 kb0 = *(const bf16x4*)(kp);
    bf16x4 vb0 = *(const bf16x4*)(vp);
    bf16x4 kb1 = *(const bf16x4*)(kp + 256);
    bf16x4 vb1 = *(const bf16x4*)(vp + 256);
    bf16x4 kb2 = *(const bf16x4*)(kp + 512);
    bf16x4 vb2 = *(const bf16x4*)(vp + 512);
    bf16x4 kb3 = *(const bf16x4*)(kp + 768);
    bf16x4 vb3 = *(const bf16x4*)(vp + 768);

    for (int c0 = 0; c0 < 48; c0 += 4) {
        attn_step(kb0, vb0, qf, oacc, lacc, ones4);
        { int n = c0 + 4; n = n >= 48 ? n - 48 : n;
          kb0 = *(const bf16x4*)(kp + n * 256); vb0 = *(const bf16x4*)(vp + n * 256); }
        attn_step(kb1, vb1, qf, oacc, lacc, ones4);
        { int n = c0 + 5; n = n >= 48 ? n - 48 : n;
          kb1 = *(const bf16x4*)(kp + n * 256); vb1 = *(const bf16x4*)(vp + n * 256); }
        attn_step(kb2, vb2, qf, oacc, lacc, ones4);
        { int n = c0 + 6; n = n >= 48 ? n - 48 : n;
          kb2 = *(const bf16x4*)(kp + n * 256); vb2 = *(const bf16x4*)(vp + n * 256); }
        attn_step(kb3, vb3, qf, oacc, lacc, ones4);
        { int n = c0 + 7; n = n >= 48 ? n - 48 : n;
          kb3 = *(const bf16x4*)(kp + n * 256); vb3 = *(const bf16x4*)(vp + n * 256); }
    }

    #pragma unroll
    for (int s = 0; s < 2; ++s) {
        const float inv = 1.f / lacc[s][0];     // row-replicated full sum
        const int q = qb * 128 + wave * 32 + s * 16 + l16;
        uint2 w2;
        w2.x = permpack(oacc[s][1] * inv, oacc[s][0] * inv);
        w2.y = permpack(oacc[s][3] * inv, oacc[s][2] * inv);
        *(uint2*)&ctx[((size_t)(b * LSEQ + q)) * EE + hoff + quad * 4] = w2;
    }
}

// ---------------------------------------------------------------------------
// Fused attn-out GEMM + LN1 + FFN + LN2 (one kernel per layer, was two).
// Phase A: Wout in LDS (overwritten later), GEMM ctx@Wout^T, +residual, LN1.
//   LN1 output y kept in registers (it IS the LN2 residual) and routed to
//   LDS (bf16) for the FFN A-fragments.
// Phase B: h = elu(y@W1^T+b1) wave-private in LDS, ffn = h@W2^T+b2, LN2.
// LDS arena 62464 B, phase-reused: [0,17920)=Wout then W1+W2; [17920,26624)
// = Ybf; [26624,31232)=Hs. 2 blocks/CU; 384 blocks -> all co-resident.
// write_f32: skip the fp32 seq write on the last layer (only bf16 needed).
// ---------------------------------------------------------------------------
#define W1OFF 0
#define W2OFF 8704
#define YOFF  17920
#define HOFF  26624
__global__ __launch_bounds__(256) void gemm_ln_ffn(
    const ushort_t* __restrict__ ctx_bf, const ushort_t* __restrict__ Wout,
    const float* __restrict__ bout,
    const float* __restrict__ g1, const float* __restrict__ be1,
    const ushort_t* __restrict__ W1, const float* __restrict__ b1,
    const ushort_t* __restrict__ W2, const float* __restrict__ b2,
    const float* __restrict__ g2, const float* __restrict__ be2,
    float* __restrict__ seq, ushort_t* __restrict__ seq_bf, int write_f32)
{
    __shared__ ushort_t S[31232];           // 62464 B
    const int t = threadIdx.x;
    const int wave = t >> 6, lane = t & 63;
    const int quad = lane >> 4, l16 = lane & 15;
    const int m0 = blockIdx.x * 64;
    const int lrow = wave * 16 + l16;
    const int m = m0 + lrow;

    // ---- stage Wout (128 x 136) into S[0..17408) ----
    for (int c = t; c < 128 * 16; c += 256) {
        int row = c >> 4, col = c & 15;
        *(bf16x8*)&S[row * 136 + col * 8] =
            *(const bf16x8*)&Wout[(size_t)row * 128 + col * 8];
    }
    __syncthreads();

    // ---- GEMM A: attn_out = ctx @ Wout^T ----
    f32x4 acc[8];
    #pragma unroll
    for (int nt = 0; nt < 8; ++nt) acc[nt] = (f32x4){0.f, 0.f, 0.f, 0.f};
    {
        const ushort_t* ap = ctx_bf + (size_t)m * EE + quad * 8;
        const ushort_t* wp = &S[l16 * 136 + quad * 8];
        #pragma unroll
        for (int k0 = 0; k0 < 128; k0 += 32) {
            bf16x8 a = *(const bf16x8*)(ap + k0);
            #pragma unroll
            for (int nt = 0; nt < 8; ++nt) {
                bf16x8 wf = *(const bf16x8*)(wp + nt * 16 * 136 + k0);
                acc[nt] = __builtin_amdgcn_mfma_f32_16x16x32_bf16(wf, a, acc[nt], 0, 0, 0);
            }
        }
    }
    __syncthreads();   // all waves done reading Wout; its LDS may be reused

    // ---- stage W1 (64x136) and W2 (128x72) over the Wout region ----
    for (int c = t; c < 64 * 16; c += 256) {
        int row = c >> 4, col = c & 15;
        *(bf16x8*)&S[W1OFF + row * 136 + col * 8] =
            *(const bf16x8*)&W1[(size_t)row * 128 + col * 8];
    }
    for (int c = t; c < 128 * 8; c += 256) {
        int row = c >> 3, col = c & 7;
        *(bf16x8*)&S[W2OFF + row * 72 + col * 8] =
            *(const bf16x8*)&W2[(size_t)row * 64 + col * 8];
    }

    // ---- epilogue A: + bias + residual, LN1 -> y (regs + LDS bf16) ----
    float y[8][4];
    float s = 0.f;
    #pragma unroll
    for (int nt = 0; nt < 8; ++nt) {
        const int nb = nt * 16 + quad * 4;
        float4 b4 = *(const float4*)&bout[nb];
        float4 r4 = *(const float4*)&seq[(size_t)m * EE + nb];
        #pragma unroll
        for (int r = 0; r < 4; ++r) {
            y[nt][r] = acc[nt][r] + ((const float*)&b4)[r] + ((const float*)&r4)[r];
            s += y[nt][r];
        }
    }
    s += __shfl_xor(s, 16);
    s += __shfl_xor(s, 32);
    float mean = s * (1.f / 128.f);
    float s2 = 0.f;
    #pragma unroll
    for (int nt = 0; nt < 8; ++nt)
        #pragma unroll
        for (int r = 0; r < 4; ++r) {
            float d = y[nt][r] - mean;
            s2 += d * d;
        }
    s2 += __shfl_xor(s2, 16);
    s2 += __shfl_xor(s2, 32);
    float rstd = 1.f / sqrtf(s2 * (1.f / 128.f) + 1e-5f);

    #pragma unroll
    for (int nt = 0; nt < 8; ++nt) {
        const int nb = nt * 16 + quad * 4;
        float4 g4 = *(const float4*)&g1[nb];
        float4 be4 = *(const float4*)&be1[nb];
        #pragma unroll
        for (int r = 0; r < 4; ++r)
            y[nt][r] = (y[nt][r] - mean) * rstd * ((const float*)&g4)[r] + ((const float*)&be4)[r];
        uint2 w2;
        w2.x = permpack(y[nt][1], y[nt][0]);
        w2.y = permpack(y[nt][3], y[nt][2]);
        *(uint2*)&S[YOFF + lrow * 136 + nb] = w2;
    }
    __syncthreads();   // Ybf + W1 + W2 visible

    // ---- GEMM 1: h = elu(y @ W1^T + b1) ----
    f32x4 acc1[4];
    #pragma unroll
    for (int nt = 0; nt < 4; ++nt) acc1[nt] = (f32x4){0.f, 0.f, 0.f, 0.f};
    {
        const ushort_t* ap1 = &S[YOFF + lrow * 136 + quad * 8];
        const ushort_t* w1p = &S[W1OFF + l16 * 136 + quad * 8];
        #pragma unroll
        for (int k0 = 0; k0 < 128; k0 += 32) {
            bf16x8 a = *(const bf16x8*)(ap1 + k0);
            #pragma unroll
            for (int nt = 0; nt < 4; ++nt) {
                bf16x8 wf = *(const bf16x8*)(w1p + nt * 16 * 136 + k0);
                acc1[nt] = __builtin_amdgcn_mfma_f32_16x16x32_bf16(wf, a, acc1[nt], 0, 0, 0);
            }
        }
    }
    #pragma unroll
    for (int nt = 0; nt < 4; ++nt) {
        const int ib = nt * 16 + quad * 4;
        float4 b4 = *(const float4*)&b1[ib];
        float hv[4];
        #pragma unroll
        for (int r = 0; r < 4; ++r) {
            float u = acc1[nt][r] + ((const float*)&b4)[r];
            hv[r] = u > 0.f ? u : expm1f(u);
        }
        uint2 w2;
        w2.x = permpack(hv[1], hv[0]);
        w2.y = permpack(hv[3], hv[2]);
        *(uint2*)&S[HOFF + lrow * 72 + ib] = w2;   // wave-private rows
    }

    // ---- GEMM 2: ffn = h @ W2^T + b2 (reads only this lane's row) ----
    f32x4 acc2[8];
    #pragma unroll
    for (int nt = 0; nt < 8; ++nt) acc2[nt] = (f32x4){0.f, 0.f, 0.f, 0.f};
    {
        const ushort_t* hp  = &S[HOFF + lrow * 72 + quad * 8];
        const ushort_t* w2p = &S[W2OFF + l16 * 72 + quad * 8];
        #pragma unroll
        for (int k0 = 0; k0 < 64; k0 += 32) {
            bf16x8 hf = *(const bf16x8*)(hp + k0);
            #pragma unroll
            for (int nt = 0; nt < 8; ++nt) {
                bf16x8 wf = *(const bf16x8*)(w2p + nt * 16 * 72 + k0);
                acc2[nt] = __builtin_amdgcn_mfma_f32_16x16x32_bf16(wf, hf, acc2[nt], 0, 0, 0);
            }
        }
    }

    // ---- epilogue B: + bias + residual(y regs), LN2, store ----
    float v[8][4];
    s = 0.f;
    #pragma unroll
    for (int nt = 0; nt < 8; ++nt) {
        const int nb = nt * 16 + quad * 4;
        float4 b4 = *(const float4*)&b2[nb];
        #pragma unroll
        for (int r = 0; r < 4; ++r) {
            v[nt][r] = acc2[nt][r] + ((const float*)&b4)[r] + y[nt][r];
            s += v[nt][r];
        }
    }
    s += __shfl_xor(s, 16);
    s += __shfl_xor(s, 32);
    mean = s * (1.f / 128.f);
    s2 = 0.f;
    #pragma unroll
    for (int nt = 0; nt < 8; ++nt)
        #pragma unroll
        for (int r = 0; r < 4; ++r) {
            float d = v[nt][r] - mean;
            s2 += d * d;
        }
    s2 += __shfl_xor(s2, 16);
    s2 += __shfl_xor(s2, 32);
    rstd = 1.f / sqrtf(s2 * (1.f / 128.f) + 1e-5f);

    #pragma unroll
    for (int nt = 0; nt < 8; ++nt) {
        const int nb = nt * 16 + quad * 4;
        float4 g4 = *(const float4*)&g2[nb];
        float4 be4 = *(const float4*)&be2[nb];
        float o[4];
        #pragma unroll
        for (int r = 0; r < 4; ++r)
            o[r] = (v[nt][r] - mean) * rstd * ((const float*)&g4)[r] + ((const float*)&be4)[r];
        if (write_f32) {
            float4 f4 = {o[0], o[1], o[2], o[3]};
            *(float4*)&seq[(size_t)m * EE + nb] = f4;
        }
        uint2 w2;
        w2.x = permpack(o[1], o[0]);
        w2.y = permpack(o[3], o[2]);
        *(uint2*)&seq_bf[(size_t)m * EE + nb] = w2;
    }
}

// ---------------------------------------------------------------------------
// Final projection, split-K MFMA. PKC 192->384: 256 blocks (1/CU), half the
// partial traffic, single-stage reduce.
// ---------------------------------------------------------------------------
#define PKC 384
#define PNBLK (KOUT / PKC)   // 256
__global__ __launch_bounds__(256) void out_gemm3(
    const ushort_t* __restrict__ seqbf, const float* __restrict__ out_w,
    float* __restrict__ part)
{
    const int t = threadIdx.x;
    const int wave = t >> 6, lane = t & 63;
    const int quad = lane >> 4, l16 = lane & 15;
    const size_t k0 = (size_t)blockIdx.x * PKC;
    const int n0 = wave * 32;

    f32x4 acc[2][2];
    #pragma unroll
    for (int mt = 0; mt < 2; ++mt)
        #pragma unroll
        for (int nt = 0; nt < 2; ++nt)
            acc[mt][nt] = (f32x4){0.f, 0.f, 0.f, 0.f};

    const ushort_t* a0p = seqbf + (size_t)l16 * KOUT + k0 + quad * 8;
    const ushort_t* a1p = a0p + (size_t)16 * KOUT;
    const float* w0p = out_w + (size_t)(n0 + l16) * KOUT + k0 + quad * 8;
    const float* w1p = w0p + (size_t)16 * KOUT;

    for (int ks = 0; ks < PKC; ks += 32) {
        bf16x8 a0 = *(const bf16x8*)(a0p + ks);
        bf16x8 a1 = *(const bf16x8*)(a1p + ks);
        float4 wa0 = *(const float4*)(w0p + ks);
        float4 wa1 = *(const float4*)(w0p + ks + 4);
        float4 wb0 = *(const float4*)(w1p + ks);
        float4 wb1 = *(const float4*)(w1p + ks + 4);
        u32x4 b0, b1;
        b0[0] = permpack(wa0.y, wa0.x); b0[1] = permpack(wa0.w, wa0.z);
        b0[2] = permpack(wa1.y, wa1.x); b0[3] = permpack(wa1.w, wa1.z);
        b1[0] = permpack(wb0.y, wb0.x); b1[1] = permpack(wb0.w, wb0.z);
        b1[2] = permpack(wb1.y, wb1.x); b1[3] = permpack(wb1.w, wb1.z);
        bf16x8 bf0 = __builtin_bit_cast(bf16x8, b0);
        bf16x8 bf1 = __builtin_bit_cast(bf16x8, b1);
        acc[0][0] = __builtin_amdgcn_mfma_f32_16x16x32_bf16(a0, bf0, acc[0][0], 0, 0, 0);
        acc[1][0] = __builtin_amdgcn_mfma_f32_16x16x32_bf16(a1, bf0, acc[1][0], 0, 0, 0);
        acc[0][1] = __builtin_amdgcn_mfma_f32_16x16x32_bf16(a0, bf1, acc[0][1], 0, 0, 0);
        acc[1][1] = __builtin_amdgcn_mfma_f32_16x16x32_bf16(a1, bf1, acc[1][1], 0, 0, 0);
    }

    float* pb = part + (size_t)blockIdx.x * (32 * 128);
    #pragma unroll
    for (int mt = 0; mt < 2; ++mt)
        #pragma unroll
        for (int nt = 0; nt < 2; ++nt)
            #pragma unroll
            for (int r = 0; r < 4; ++r)
                pb[(mt * 16 + quad * 4 + r) * 128 + n0 + nt * 16 + l16] = acc[mt][nt][r];
}

// ---------------------------------------------------------------------------
// Single-stage reduction over 256 split-K partials (4 MB read, 16 blocks).
// ---------------------------------------------------------------------------
__global__ __launch_bounds__(256) void out_reduce(
    const float* __restrict__ part, const float* __restrict__ out_b,
    float* __restrict__ out)
{
    const int i = blockIdx.x * 256 + threadIdx.x;
    const float* p = part + i;
    float s0 = 0.f, s1 = 0.f, s2 = 0.f, s3 = 0.f;
    for (int blk = 0; blk < PNBLK; blk += 4) {
        s0 += p[(size_t)blk * 4096];
        s1 += p[(size_t)(blk + 1) * 4096];
        s2 += p[(size_t)(blk + 2) * 4096];
        s3 += p[(size_t)(blk + 3) * 4096];
    }
    out[i] = out_b[i & (OUTN - 1)] + ((s0 + s1) + (s2 + s3));
}

// ---------------------------------------------------------------------------
extern "C" void kernel_launch(void* const* d_in, const int* in_sizes, int n_in,
                              void* d_out, int out_size, void* d_ws, size_t ws_size,
                              hipStream_t stream)
{
    const float* x          = (const float*)d_in[0];
    const float* prototypes = (const float*)d_in[1];
    const float* emb_w      = (const float*)d_in[2];
    const float* emb_b      = (const float*)d_in[3];
    const float* proj_w     = (const float*)d_in[4];
    const float* proj_b     = (const float*)d_in[5];
    const float* in_proj_w  = (const float*)d_in[6];
    const float* in_proj_b  = (const float*)d_in[7];
    const float* out_proj_w = (const float*)d_in[8];
    const float* out_proj_b = (const float*)d_in[9];
    const float* ln1_s      = (const float*)d_in[10];
    const float* ln1_b      = (const float*)d_in[11];
    const float* ffn_w1     = (const float*)d_in[12];
    const float* ffn_b1     = (const float*)d_in[13];
    const float* ffn_w2     = (const float*)d_in[14];
    const float* ffn_b2     = (const float*)d_in[15];
    const float* ln2_s      = (const float*)d_in[16];
    const float* ln2_b      = (const float*)d_in[17];
    const float* out_w      = (const float*)d_in[18];
    const float* out_b      = (const float*)d_in[19];
    float* out = (float*)d_out;
    char* base = (char*)d_ws;

    float*    seq    = (float*)base;                        // 12,582,912
    float*    tmp    = (float*)(base + 12582912);           // (= part, 4 MB)
    ushort_t* seq_bf = (ushort_t*)(base + 25165824);        //  6,291,456
    ushort_t* q_bf   = (ushort_t*)(base + 31457280);        //  6,291,456
    ushort_t* k2     = (ushort_t*)(base + 37748736);        //  6,291,456
    ushort_t* v2     = (ushort_t*)(base + 44040192);        //  6,291,456
    ushort_t* ctx_bf = (ushort_t*)(base + 50331648);        //  6,291,456
    ushort_t* w_bf   = (ushort_t*)(base + 56623104);        //    327,680
    float*    part   = tmp;                                 // 4 MB
    float*    peT    = (float*)(base + 12582912 + 9437184); // 384 KB
    (void)ws_size;

    ushort_t* w_in  = w_bf;            // [2][384][128]
    ushort_t* w_out = w_bf + 98304;    // [2][128][128]
    ushort_t* w_f1  = w_bf + 131072;   // [2][64][128]
    ushort_t* w_f2  = w_bf + 147456;   // [2][128][64]

    // 163840 cast elements + 98304 PE entries = 262144 = 1024 * 256
    cast_all_kernel<<<1024, 256, 0, stream>>>(
        in_proj_w, 98304, out_proj_w, 32768, ffn_w1, 16384, ffn_w2, 16384,
        w_in, w_out, w_f1, w_f2, peT);

    embed_kernel<<<ROWS, 128, 0, stream>>>(x, prototypes, emb_w, emb_b,
                                           proj_w, proj_b, peT, seq, seq_bf);

    for (int l = 0; l < 2; ++l) {
        gemm_qkv<<<dim3(6, 192), 256, 0, stream>>>(
            seq_bf, w_in + (size_t)l * 49152, in_proj_b + l * 384,
            q_bf, k2, v2);
        attention_mfma<<<dim3(BB * HH, 6), 256, 0, stream>>>(q_bf, k2, v2, ctx_bf);
        // seq = LN2(LN1(seq + ctx@Wout^T + b) + FFN(...)) fully fused
        gemm_ln_ffn<<<ROWS / 64, 256, 0, stream>>>(
            ctx_bf, w_out + (size_t)l * 16384, out_proj_b + l * 128,
            ln1_s + l * EE, ln1_b + l * EE,
            w_f1 + (size_t)l * 8192, ffn_b1 + l * II,
            w_f2 + (size_t)l * 8192, ffn_b2 + l * EE,
            ln2_s + l * EE, ln2_b + l * EE,
            seq, seq_bf, l == 0 ? 1 : 0);
    }

    out_gemm3<<<PNBLK, 256, 0, stream>>>(seq_bf, out_w, part);
    out_reduce<<<BB * OUTN / 256, 256, 0, stream>>>(part, out_b, out);
}

// Round 4
// 260.942 us; speedup vs baseline: 1.3282x; 1.0824x over previous
//
#include <hip/hip_runtime.h>
#include <hip/hip_bf16.h>
#include <math.h>

typedef unsigned short ushort_t;
typedef unsigned int uint_t;

// Problem constants
#define BB 32
#define PP 6
#define DD 96
#define EE 128
#define HH 8
#define II 64
#define KK 32
#define LSEQ 768            // N*D
#define ROWS (BB * LSEQ)    // 24576 token rows
#define OUTN 128
#define KOUT (LSEQ * EE)    // 98304

using bf16x8 = __attribute__((ext_vector_type(8))) short;
using bf16x4 = __attribute__((ext_vector_type(4))) short;
using f32x4  = __attribute__((ext_vector_type(4))) float;
using u32x4  = __attribute__((ext_vector_type(4))) uint_t;

__device__ __forceinline__ ushort_t f2b(float f) {
    __hip_bfloat16 h = __float2bfloat16(f);
    return *reinterpret_cast<ushort_t*>(&h);
}
// pack two fp32 -> (bf16(hi)<<16)|bf16(lo) by TRUNCATION: one v_perm_b32.
__device__ __forceinline__ uint_t permpack(float hi, float lo) {
    return __builtin_amdgcn_perm(__builtin_bit_cast(uint_t, hi),
                                 __builtin_bit_cast(uint_t, lo), 0x07060302u);
}

// ---------------------------------------------------------------------------
// Merged cast + embed. Blocks [0,320): cast fp32->bf16 weights (163840 elems).
// Blocks [320,3392): embed, ONE WAVE PER ROW (8 rows/block, 512 thr), zero
// LDS / zero barriers. All 64 lanes duplicate the 32 proto sims, xor-butterfly
// argmax, selected-proto norm recomputed from L1-hot global. PE inline with
// fast trig (2 values/lane).
// ---------------------------------------------------------------------------
#define NCAST 320
__global__ __launch_bounds__(512) void cast_embed_kernel(
    const float* __restrict__ s0, int n0, const float* __restrict__ s1, int n1,
    const float* __restrict__ s2, int n2, const float* __restrict__ s3, int n3,
    ushort_t* __restrict__ d0, ushort_t* __restrict__ d1,
    ushort_t* __restrict__ d2, ushort_t* __restrict__ d3,
    const float* __restrict__ x, const float* __restrict__ prot,
    const float* __restrict__ emb_w, const float* __restrict__ emb_b,
    const float* __restrict__ proj_w, const float* __restrict__ proj_b,
    float* __restrict__ seq, ushort_t* __restrict__ seq_bf)
{
    if (blockIdx.x < NCAST) {
        int i = blockIdx.x * 512 + threadIdx.x;
        if (i < n0) { d0[i] = f2b(s0[i]); return; }
        i -= n0;
        if (i < n1) { d1[i] = f2b(s1[i]); return; }
        i -= n1;
        if (i < n2) { d2[i] = f2b(s2[i]); return; }
        i -= n2;
        if (i < n3) { d3[i] = f2b(s3[i]); }
        return;
    }

    const int wave = threadIdx.x >> 6, lane = threadIdx.x & 63;
    const int r = (blockIdx.x - NCAST) * 8 + wave;
    const int d = r % DD;
    const int lpos = r % LSEQ;

    float xr[PP];
    float nx = 0.f;
    #pragma unroll
    for (int p = 0; p < PP; ++p) { xr[p] = x[r * PP + p]; nx += xr[p] * xr[p]; }
    const float xinv = 1.f / fmaxf(sqrtf(nx), 1e-12f);

    // proto sims, duplicated across the two 32-lane halves
    const int tk = lane & 31;
    const float* pr = prot + (d * KK + tk) * PP;
    float np2 = 0.f, dot = 0.f;
    #pragma unroll
    for (int p = 0; p < PP; ++p) {
        float pv = pr[p];
        np2 += pv * pv;
        dot += xr[p] * pv;
    }
    const float pinv = 1.f / fmaxf(sqrtf(np2), 1e-12f);
    float sim = dot * xinv * pinv;
    int k = tk;
    #pragma unroll
    for (int off = 16; off; off >>= 1) {
        float osim = __shfl_xor(sim, off);
        int   ok   = __shfl_xor(k, off);
        if (osim > sim || (osim == sim && ok < k)) { sim = osim; k = ok; }
    }
    // selected proto, normalized (recompute norm; all lanes agree on k)
    const float* sr = prot + (d * KK + k) * PP;
    float sp[PP], sn2 = 0.f;
    #pragma unroll
    for (int p = 0; p < PP; ++p) { sp[p] = sr[p]; sn2 += sp[p] * sp[p]; }
    const float spinv = 1.f / fmaxf(sqrtf(sn2), 1e-12f);

    #pragma unroll
    for (int c = 0; c < 2; ++c) {
        const int t = lane + c * 64;
        float acc = emb_b[t] + proj_b[t];
        #pragma unroll
        for (int p = 0; p < PP; ++p) {
            acc = fmaf(xr[p], emb_w[t * PP + p], acc);
            acc = fmaf(sp[p] * spinv, proj_w[t * PP + p], acc);
        }
        const float twoj = (float)((t >> 1) * 2);
        const float div = __expf(twoj * (-9.210340371976184f / 128.0f));
        const float ang = (float)lpos * div;
        const float pe = (t & 1) ? __cosf(ang) : __sinf(ang);
        const float v = acc + pe;
        seq[(size_t)r * EE + t] = v;
        seq_bf[(size_t)r * EE + t] = f2b(v);
    }
}

// ---------------------------------------------------------------------------
// QKV GEMM with attention-native output layouts (32-kv chunk variants).
//   Q -> q_bf[row][128], pre-scaled by 0.25*log2e
//   K -> k2[bh][c32][half][dg=quad][m][4dims], where row m carries
//        kv = c32*32 + (m>>2)*8 + half*4 + (m&3)  (so the two QK MFMAs'
//        sv quads concatenate into the x32 PV B-fragment per lane)
//   V -> v2[bh][c32][d][kk=kv%32]
// ---------------------------------------------------------------------------
__global__ __launch_bounds__(256) void gemm_qkv(
    const ushort_t* __restrict__ A, const ushort_t* __restrict__ W,
    const float* __restrict__ bias,
    ushort_t* __restrict__ q_bf, ushort_t* __restrict__ k2,
    ushort_t* __restrict__ v2)
{
    __shared__ ushort_t Ws[64 * 136];   // kp = 136 (K=128)
    const int t = threadIdx.x;
    const int wave = t >> 6, lane = t & 63;
    const int quad = lane >> 4, l16 = lane & 15;
    const int m0 = blockIdx.y * 128, n0 = blockIdx.x * 64;

    for (int c = t; c < 64 * 16; c += 256) {
        int row = c >> 4, col = c & 15;
        *(bf16x8*)&Ws[row * 136 + col * 8] =
            *(const bf16x8*)&W[(size_t)(n0 + row) * 128 + col * 8];
    }
    __syncthreads();

    f32x4 acc[2][4];
    #pragma unroll
    for (int s = 0; s < 2; ++s)
        #pragma unroll
        for (int nt = 0; nt < 4; ++nt)
            acc[s][nt] = (f32x4){0.f, 0.f, 0.f, 0.f};

    const ushort_t* a0p = A + (size_t)(m0 + wave * 32 + l16) * 128 + quad * 8;
    const ushort_t* a1p = a0p + (size_t)16 * 128;
    const ushort_t* wp  = &Ws[l16 * 136 + quad * 8];

    #pragma unroll
    for (int k0 = 0; k0 < 128; k0 += 32) {
        bf16x8 a0 = *(const bf16x8*)(a0p + k0);
        bf16x8 a1 = *(const bf16x8*)(a1p + k0);
        #pragma unroll
        for (int nt = 0; nt < 4; ++nt) {
            bf16x8 wf = *(const bf16x8*)(wp + nt * 16 * 136 + k0);
            acc[0][nt] = __builtin_amdgcn_mfma_f32_16x16x32_bf16(wf, a0, acc[0][nt], 0, 0, 0);
            acc[1][nt] = __builtin_amdgcn_mfma_f32_16x16x32_bf16(wf, a1, acc[1][nt], 0, 0, 0);
        }
    }

    const int b = blockIdx.y / 6;            // 6 m-blocks per batch (768/128)
    #pragma unroll
    for (int s = 0; s < 2; ++s) {
        const int m = m0 + wave * 32 + s * 16 + l16;
        const int l = m - b * LSEQ;          // position within sequence
        const int c32 = l >> 5, u = l & 31;
        #pragma unroll
        for (int nt = 0; nt < 4; ++nt) {
            const int nb = n0 + nt * 16 + quad * 4;
            float4 b4 = *(const float4*)&bias[nb];
            float v[4];
            #pragma unroll
            for (int r = 0; r < 4; ++r)
                v[r] = acc[s][nt][r] + ((const float*)&b4)[r];

            if (n0 < 128) {
                // Q: pre-scale by 1/sqrt(16) * log2(e)
                #pragma unroll
                for (int r = 0; r < 4; ++r) v[r] *= 0.36067376022224085f;
                uint2 w2;
                w2.x = permpack(v[1], v[0]);
                w2.y = permpack(v[3], v[2]);
                *(uint2*)&q_bf[(size_t)m * EE + nb] = w2;
            } else if (n0 < 256) {
                const int h = ((n0 - 128) >> 4) + nt;
                const int half = (u >> 2) & 1;
                const int mm = ((u >> 3) << 2) | (u & 3);
                uint2 w2;
                w2.x = permpack(v[1], v[0]);
                w2.y = permpack(v[3], v[2]);
                *(uint2*)&k2[((((((size_t)(b * HH + h)) * 24 + c32) * 2 + half) * 4 + quad) * 16 + mm) * 4] = w2;
            } else {
                const int h = ((n0 - 256) >> 4) + nt;
                const size_t vb = (((size_t)(b * HH + h)) * 24 + c32) * 512;
                #pragma unroll
                for (int r = 0; r < 4; ++r)
                    v2[vb + (quad * 4 + r) * 32 + u] = f2b(v[r]);
            }
        }
    }
}

// ---------------------------------------------------------------------------
// MFMA flash attention v9: 32-kv chunks. QK = 2x 16x16x16 (head-dim=16),
// PV + ones-rowsum = 16x16x32 over the full 32-kv chunk (K-row permutation
// in k2 makes the two sv quads concatenate per-lane into the x32 B-frag).
// 24 chunks, 3-deep register prefetch, zero LDS / zero barriers.
// ---------------------------------------------------------------------------
__device__ __forceinline__ void attn_step32(
    bf16x4 kf0, bf16x4 kf1, bf16x8 vf, const bf16x4 (&qf)[2],
    f32x4 (&oacc)[2], f32x4 (&lacc)[2], bf16x8 ones8)
{
    const f32x4 zero4 = (f32x4){0.f, 0.f, 0.f, 0.f};
    #pragma unroll
    for (int s = 0; s < 2; ++s) {
        f32x4 sv0 = __builtin_amdgcn_mfma_f32_16x16x16bf16_1k(kf0, qf[s], zero4, 0, 0, 0);
        f32x4 sv1 = __builtin_amdgcn_mfma_f32_16x16x16bf16_1k(kf1, qf[s], zero4, 0, 0, 0);
        float e0 = __builtin_amdgcn_exp2f(sv0[0]);
        float e1 = __builtin_amdgcn_exp2f(sv0[1]);
        float e2 = __builtin_amdgcn_exp2f(sv0[2]);
        float e3 = __builtin_amdgcn_exp2f(sv0[3]);
        float e4 = __builtin_amdgcn_exp2f(sv1[0]);
        float e5 = __builtin_amdgcn_exp2f(sv1[1]);
        float e6 = __builtin_amdgcn_exp2f(sv1[2]);
        float e7 = __builtin_amdgcn_exp2f(sv1[3]);
        u32x4 pu;
        pu[0] = permpack(e1, e0);
        pu[1] = permpack(e3, e2);
        pu[2] = permpack(e5, e4);
        pu[3] = permpack(e7, e6);
        bf16x8 pf = __builtin_bit_cast(bf16x8, pu);
        oacc[s] = __builtin_amdgcn_mfma_f32_16x16x32_bf16(vf, pf, oacc[s], 0, 0, 0);
        lacc[s] = __builtin_amdgcn_mfma_f32_16x16x32_bf16(ones8, pf, lacc[s], 0, 0, 0);
    }
}

__global__ __launch_bounds__(256) void attention_mfma(
    const ushort_t* __restrict__ q_bf, const ushort_t* __restrict__ k2,
    const ushort_t* __restrict__ v2, ushort_t* __restrict__ ctx)
{
    const int bh = blockIdx.x;
    const int b = bh & 31, h = bh >> 5;     // XCD swizzle: id%8 == b%8
    const int qb = blockIdx.y;              // 0..5, 128 q each
    const int t = threadIdx.x;
    const int wave = t >> 6, lane = t & 63;
    const int quad = lane >> 4, l16 = lane & 15;
    const int hoff = h * 16;

    // Q fragments (one-time gather)
    bf16x4 qf[2];
    #pragma unroll
    for (int s = 0; s < 2; ++s) {
        int row = b * LSEQ + qb * 128 + wave * 32 + s * 16 + l16;
        qf[s] = *(const bf16x4*)&q_bf[(size_t)row * EE + hoff + quad * 4];
    }

    const int bhn = b * HH + h;
    const ushort_t* kp = k2 + (size_t)bhn * 12288 + quad * 64 + l16 * 4;
    const ushort_t* vp = v2 + (size_t)bhn * 12288 + l16 * 32 + quad * 8;

    f32x4 oacc[2], lacc[2];
    oacc[0] = (f32x4){0.f, 0.f, 0.f, 0.f};
    oacc[1] = (f32x4){0.f, 0.f, 0.f, 0.f};
    lacc[0] = (f32x4){0.f, 0.f, 0.f, 0.f};
    lacc[1] = (f32x4){0.f, 0.f, 0.f, 0.f};
    bf16x8 ones8;
    #pragma unroll
    for (int j = 0; j < 8; ++j) ones8[j] = (short)0x3F80;   // bf16 1.0

    bf16x4 k0a = *(const bf16x4*)(kp);
    bf16x4 k1a = *(const bf16x4*)(kp + 256);
    bf16x8 va  = *(const bf16x8*)(vp);
    bf16x4 k0b = *(const bf16x4*)(kp + 512);
    bf16x4 k1b = *(const bf16x4*)(kp + 768);
    bf16x8 vb  = *(const bf16x8*)(vp + 512);
    bf16x4 k0c = *(const bf16x4*)(kp + 1024);
    bf16x4 k1c = *(const bf16x4*)(kp + 1280);
    bf16x8 vc  = *(const bf16x8*)(vp + 1024);

    for (int c0 = 0; c0 < 24; c0 += 3) {
        attn_step32(k0a, k1a, va, qf, oacc, lacc, ones8);
        { int n = c0 + 3; if (n >= 24) n -= 24;
          k0a = *(const bf16x4*)(kp + n * 512);
          k1a = *(const bf16x4*)(kp + n * 512 + 256);
          va  = *(const bf16x8*)(vp + n * 512); }
        attn_step32(k0b, k1b, vb, qf, oacc, lacc, ones8);
        { int n = c0 + 4; if (n >= 24) n -= 24;
          k0b = *(const bf16x4*)(kp + n * 512);
          k1b = *(const bf16x4*)(kp + n * 512 + 256);
          vb  = *(const bf16x8*)(vp + n * 512); }
        attn_step32(k0c, k1c, vc, qf, oacc, lacc, ones8);
        { int n = c0 + 5; if (n >= 24) n -= 24;
          k0c = *(const bf16x4*)(kp + n * 512);
          k1c = *(const bf16x4*)(kp + n * 512 + 256);
          vc  = *(const bf16x8*)(vp + n * 512); }
    }

    #pragma unroll
    for (int s = 0; s < 2; ++s) {
        const float inv = 1.f / lacc[s][0];     // row-replicated full sum
        const int q = qb * 128 + wave * 32 + s * 16 + l16;
        uint2 w2;
        w2.x = permpack(oacc[s][1] * inv, oacc[s][0] * inv);
        w2.y = permpack(oacc[s][3] * inv, oacc[s][2] * inv);
        *(uint2*)&ctx[((size_t)(b * LSEQ + q)) * EE + hoff + quad * 4] = w2;
    }
}

// ---------------------------------------------------------------------------
// Fused attn-out GEMM + LN1 + FFN + LN2 (unchanged from round 3).
// ---------------------------------------------------------------------------
#define W1OFF 0
#define W2OFF 8704
#define YOFF  17920
#define HOFF  26624
__global__ __launch_bounds__(256) void gemm_ln_ffn(
    const ushort_t* __restrict__ ctx_bf, const ushort_t* __restrict__ Wout,
    const float* __restrict__ bout,
    const float* __restrict__ g1, const float* __restrict__ be1,
    const ushort_t* __restrict__ W1, const float* __restrict__ b1,
    const ushort_t* __restrict__ W2, const float* __restrict__ b2,
    const float* __restrict__ g2, const float* __restrict__ be2,
    float* __restrict__ seq, ushort_t* __restrict__ seq_bf, int write_f32)
{
    __shared__ ushort_t S[31232];           // 62464 B
    const int t = threadIdx.x;
    const int wave = t >> 6, lane = t & 63;
    const int quad = lane >> 4, l16 = lane & 15;
    const int m0 = blockIdx.x * 64;
    const int lrow = wave * 16 + l16;
    const int m = m0 + lrow;

    // ---- stage Wout (128 x 136) into S[0..17408) ----
    for (int c = t; c < 128 * 16; c += 256) {
        int row = c >> 4, col = c & 15;
        *(bf16x8*)&S[row * 136 + col * 8] =
            *(const bf16x8*)&Wout[(size_t)row * 128 + col * 8];
    }
    __syncthreads();

    // ---- GEMM A: attn_out = ctx @ Wout^T ----
    f32x4 acc[8];
    #pragma unroll
    for (int nt = 0; nt < 8; ++nt) acc[nt] = (f32x4){0.f, 0.f, 0.f, 0.f};
    {
        const ushort_t* ap = ctx_bf + (size_t)m * EE + quad * 8;
        const ushort_t* wp = &S[l16 * 136 + quad * 8];
        #pragma unroll
        for (int k0 = 0; k0 < 128; k0 += 32) {
            bf16x8 a = *(const bf16x8*)(ap + k0);
            #pragma unroll
            for (int nt = 0; nt < 8; ++nt) {
                bf16x8 wf = *(const bf16x8*)(wp + nt * 16 * 136 + k0);
                acc[nt] = __builtin_amdgcn_mfma_f32_16x16x32_bf16(wf, a, acc[nt], 0, 0, 0);
            }
        }
    }
    __syncthreads();   // all waves done reading Wout; its LDS may be reused

    // ---- stage W1 (64x136) and W2 (128x72) over the Wout region ----
    for (int c = t; c < 64 * 16; c += 256) {
        int row = c >> 4, col = c & 15;
        *(bf16x8*)&S[W1OFF + row * 136 + col * 8] =
            *(const bf16x8*)&W1[(size_t)row * 128 + col * 8];
    }
    for (int c = t; c < 128 * 8; c += 256) {
        int row = c >> 3, col = c & 7;
        *(bf16x8*)&S[W2OFF + row * 72 + col * 8] =
            *(const bf16x8*)&W2[(size_t)row * 64 + col * 8];
    }

    // ---- epilogue A: + bias + residual, LN1 -> y (regs + LDS bf16) ----
    float y[8][4];
    float s = 0.f;
    #pragma unroll
    for (int nt = 0; nt < 8; ++nt) {
        const int nb = nt * 16 + quad * 4;
        float4 b4 = *(const float4*)&bout[nb];
        float4 r4 = *(const float4*)&seq[(size_t)m * EE + nb];
        #pragma unroll
        for (int r = 0; r < 4; ++r) {
            y[nt][r] = acc[nt][r] + ((const float*)&b4)[r] + ((const float*)&r4)[r];
            s += y[nt][r];
        }
    }
    s += __shfl_xor(s, 16);
    s += __shfl_xor(s, 32);
    float mean = s * (1.f / 128.f);
    float s2 = 0.f;
    #pragma unroll
    for (int nt = 0; nt < 8; ++nt)
        #pragma unroll
        for (int r = 0; r < 4; ++r) {
            float d = y[nt][r] - mean;
            s2 += d * d;
        }
    s2 += __shfl_xor(s2, 16);
    s2 += __shfl_xor(s2, 32);
    float rstd = 1.f / sqrtf(s2 * (1.f / 128.f) + 1e-5f);

    #pragma unroll
    for (int nt = 0; nt < 8; ++nt) {
        const int nb = nt * 16 + quad * 4;
        float4 g4 = *(const float4*)&g1[nb];
        float4 be4 = *(const float4*)&be1[nb];
        #pragma unroll
        for (int r = 0; r < 4; ++r)
            y[nt][r] = (y[nt][r] - mean) * rstd * ((const float*)&g4)[r] + ((const float*)&be4)[r];
        uint2 w2;
        w2.x = permpack(y[nt][1], y[nt][0]);
        w2.y = permpack(y[nt][3], y[nt][2]);
        *(uint2*)&S[YOFF + lrow * 136 + nb] = w2;
    }
    __syncthreads();   // Ybf + W1 + W2 visible

    // ---- GEMM 1: h = elu(y @ W1^T + b1) ----
    f32x4 acc1[4];
    #pragma unroll
    for (int nt = 0; nt < 4; ++nt) acc1[nt] = (f32x4){0.f, 0.f, 0.f, 0.f};
    {
        const ushort_t* ap1 = &S[YOFF + lrow * 136 + quad * 8];
        const ushort_t* w1p = &S[W1OFF + l16 * 136 + quad * 8];
        #pragma unroll
        for (int k0 = 0; k0 < 128; k0 += 32) {
            bf16x8 a = *(const bf16x8*)(ap1 + k0);
            #pragma unroll
            for (int nt = 0; nt < 4; ++nt) {
                bf16x8 wf = *(const bf16x8*)(w1p + nt * 16 * 136 + k0);
                acc1[nt] = __builtin_amdgcn_mfma_f32_16x16x32_bf16(wf, a, acc1[nt], 0, 0, 0);
            }
        }
    }
    #pragma unroll
    for (int nt = 0; nt < 4; ++nt) {
        const int ib = nt * 16 + quad * 4;
        float4 b4 = *(const float4*)&b1[ib];
        float hv[4];
        #pragma unroll
        for (int r = 0; r < 4; ++r) {
            float u = acc1[nt][r] + ((const float*)&b4)[r];
            hv[r] = u > 0.f ? u : expm1f(u);
        }
        uint2 w2;
        w2.x = permpack(hv[1], hv[0]);
        w2.y = permpack(hv[3], hv[2]);
        *(uint2*)&S[HOFF + lrow * 72 + ib] = w2;   // wave-private rows
    }

    // ---- GEMM 2: ffn = h @ W2^T + b2 (reads only this lane's row) ----
    f32x4 acc2[8];
    #pragma unroll
    for (int nt = 0; nt < 8; ++nt) acc2[nt] = (f32x4){0.f, 0.f, 0.f, 0.f};
    {
        const ushort_t* hp  = &S[HOFF + lrow * 72 + quad * 8];
        const ushort_t* w2p = &S[W2OFF + l16 * 72 + quad * 8];
        #pragma unroll
        for (int k0 = 0; k0 < 64; k0 += 32) {
            bf16x8 hf = *(const bf16x8*)(hp + k0);
            #pragma unroll
            for (int nt = 0; nt < 8; ++nt) {
                bf16x8 wf = *(const bf16x8*)(w2p + nt * 16 * 72 + k0);
                acc2[nt] = __builtin_amdgcn_mfma_f32_16x16x32_bf16(wf, hf, acc2[nt], 0, 0, 0);
            }
        }
    }

    // ---- epilogue B: + bias + residual(y regs), LN2, store ----
    float v[8][4];
    s = 0.f;
    #pragma unroll
    for (int nt = 0; nt < 8; ++nt) {
        const int nb = nt * 16 + quad * 4;
        float4 b4 = *(const float4*)&b2[nb];
        #pragma unroll
        for (int r = 0; r < 4; ++r) {
            v[nt][r] = acc2[nt][r] + ((const float*)&b4)[r] + y[nt][r];
            s += v[nt][r];
        }
    }
    s += __shfl_xor(s, 16);
    s += __shfl_xor(s, 32);
    mean = s * (1.f / 128.f);
    s2 = 0.f;
    #pragma unroll
    for (int nt = 0; nt < 8; ++nt)
        #pragma unroll
        for (int r = 0; r < 4; ++r) {
            float d = v[nt][r] - mean;
            s2 += d * d;
        }
    s2 += __shfl_xor(s2, 16);
    s2 += __shfl_xor(s2, 32);
    rstd = 1.f / sqrtf(s2 * (1.f / 128.f) + 1e-5f);

    #pragma unroll
    for (int nt = 0; nt < 8; ++nt) {
        const int nb = nt * 16 + quad * 4;
        float4 g4 = *(const float4*)&g2[nb];
        float4 be4 = *(const float4*)&be2[nb];
        float o[4];
        #pragma unroll
        for (int r = 0; r < 4; ++r)
            o[r] = (v[nt][r] - mean) * rstd * ((const float*)&g4)[r] + ((const float*)&be4)[r];
        if (write_f32) {
            float4 f4 = {o[0], o[1], o[2], o[3]};
            *(float4*)&seq[(size_t)m * EE + nb] = f4;
        }
        uint2 w2;
        w2.x = permpack(o[1], o[0]);
        w2.y = permpack(o[3], o[2]);
        *(uint2*)&seq_bf[(size_t)m * EE + nb] = w2;
    }
}

// ---------------------------------------------------------------------------
// Final projection, split-K MFMA (unchanged).
// ---------------------------------------------------------------------------
#define PKC 384
#define PNBLK (KOUT / PKC)   // 256
__global__ __launch_bounds__(256) void out_gemm3(
    const ushort_t* __restrict__ seqbf, const float* __restrict__ out_w,
    float* __restrict__ part)
{
    const int t = threadIdx.x;
    const int wave = t >> 6, lane = t & 63;
    const int quad = lane >> 4, l16 = lane & 15;
    const size_t k0 = (size_t)blockIdx.x * PKC;
    const int n0 = wave * 32;

    f32x4 acc[2][2];
    #pragma unroll
    for (int mt = 0; mt < 2; ++mt)
        #pragma unroll
        for (int nt = 0; nt < 2; ++nt)
            acc[mt][nt] = (f32x4){0.f, 0.f, 0.f, 0.f};

    const ushort_t* a0p = seqbf + (size_t)l16 * KOUT + k0 + quad * 8;
    const ushort_t* a1p = a0p + (size_t)16 * KOUT;
    const float* w0p = out_w + (size_t)(n0 + l16) * KOUT + k0 + quad * 8;
    const float* w1p = w0p + (size_t)16 * KOUT;

    for (int ks = 0; ks < PKC; ks += 32) {
        bf16x8 a0 = *(const bf16x8*)(a0p + ks);
        bf16x8 a1 = *(const bf16x8*)(a1p + ks);
        float4 wa0 = *(const float4*)(w0p + ks);
        float4 wa1 = *(const float4*)(w0p + ks + 4);
        float4 wb0 = *(const float4*)(w1p + ks);
        float4 wb1 = *(const float4*)(w1p + ks + 4);
        u32x4 b0, b1;
        b0[0] = permpack(wa0.y, wa0.x); b0[1] = permpack(wa0.w, wa0.z);
        b0[2] = permpack(wa1.y, wa1.x); b0[3] = permpack(wa1.w, wa1.z);
        b1[0] = permpack(wb0.y, wb0.x); b1[1] = permpack(wb0.w, wb0.z);
        b1[2] = permpack(wb1.y, wb1.x); b1[3] = permpack(wb1.w, wb1.z);
        bf16x8 bf0 = __builtin_bit_cast(bf16x8, b0);
        bf16x8 bf1 = __builtin_bit_cast(bf16x8, b1);
        acc[0][0] = __builtin_amdgcn_mfma_f32_16x16x32_bf16(a0, bf0, acc[0][0], 0, 0, 0);
        acc[1][0] = __builtin_amdgcn_mfma_f32_16x16x32_bf16(a1, bf0, acc[1][0], 0, 0, 0);
        acc[0][1] = __builtin_amdgcn_mfma_f32_16x16x32_bf16(a0, bf1, acc[0][1], 0, 0, 0);
        acc[1][1] = __builtin_amdgcn_mfma_f32_16x16x32_bf16(a1, bf1, acc[1][1], 0, 0, 0);
    }

    float* pb = part + (size_t)blockIdx.x * (32 * 128);
    #pragma unroll
    for (int mt = 0; mt < 2; ++mt)
        #pragma unroll
        for (int nt = 0; nt < 2; ++nt)
            #pragma unroll
            for (int r = 0; r < 4; ++r)
                pb[(mt * 16 + quad * 4 + r) * 128 + n0 + nt * 16 + l16] = acc[mt][nt][r];
}

// ---------------------------------------------------------------------------
// Two-stage reduction over 256 split-K partials.
// Stage 1: 128 blocks (16 elem-groups x 8 splits), each sums 32 partials.
// Stage 2: 16 blocks sum the 8 splits.
// ---------------------------------------------------------------------------
__global__ __launch_bounds__(256) void out_reduce1(
    const float* __restrict__ part, float* __restrict__ part2)
{
    const int g = blockIdx.x & 15, sp = blockIdx.x >> 4;   // sp in 0..7
    const int i = g * 256 + threadIdx.x;
    const float* p = part + (size_t)sp * 32 * 4096 + i;
    float s0 = 0.f, s1 = 0.f, s2 = 0.f, s3 = 0.f;
    for (int blk = 0; blk < 32; blk += 4) {
        s0 += p[(size_t)blk * 4096];
        s1 += p[(size_t)(blk + 1) * 4096];
        s2 += p[(size_t)(blk + 2) * 4096];
        s3 += p[(size_t)(blk + 3) * 4096];
    }
    part2[sp * 4096 + i] = (s0 + s1) + (s2 + s3);
}

__global__ __launch_bounds__(256) void out_reduce2(
    const float* __restrict__ part2, const float* __restrict__ out_b,
    float* __restrict__ out)
{
    const int i = blockIdx.x * 256 + threadIdx.x;
    float s = 0.f;
    #pragma unroll
    for (int sp = 0; sp < 8; ++sp) s += part2[sp * 4096 + i];
    out[i] = out_b[i & (OUTN - 1)] + s;
}

// ---------------------------------------------------------------------------
extern "C" void kernel_launch(void* const* d_in, const int* in_sizes, int n_in,
                              void* d_out, int out_size, void* d_ws, size_t ws_size,
                              hipStream_t stream)
{
    const float* x          = (const float*)d_in[0];
    const float* prototypes = (const float*)d_in[1];
    const float* emb_w      = (const float*)d_in[2];
    const float* emb_b      = (const float*)d_in[3];
    const float* proj_w     = (const float*)d_in[4];
    const float* proj_b     = (const float*)d_in[5];
    const float* in_proj_w  = (const float*)d_in[6];
    const float* in_proj_b  = (const float*)d_in[7];
    const float* out_proj_w = (const float*)d_in[8];
    const float* out_proj_b = (const float*)d_in[9];
    const float* ln1_s      = (const float*)d_in[10];
    const float* ln1_b      = (const float*)d_in[11];
    const float* ffn_w1     = (const float*)d_in[12];
    const float* ffn_b1     = (const float*)d_in[13];
    const float* ffn_w2     = (const float*)d_in[14];
    const float* ffn_b2     = (const float*)d_in[15];
    const float* ln2_s      = (const float*)d_in[16];
    const float* ln2_b      = (const float*)d_in[17];
    const float* out_w      = (const float*)d_in[18];
    const float* out_b      = (const float*)d_in[19];
    float* out = (float*)d_out;
    char* base = (char*)d_ws;

    float*    seq    = (float*)base;                        // 12,582,912
    float*    tmp    = (float*)(base + 12582912);           // (= part, 4 MB)
    ushort_t* seq_bf = (ushort_t*)(base + 25165824);        //  6,291,456
    ushort_t* q_bf   = (ushort_t*)(base + 31457280);        //  6,291,456
    ushort_t* k2     = (ushort_t*)(base + 37748736);        //  6,291,456
    ushort_t* v2     = (ushort_t*)(base + 44040192);        //  6,291,456
    ushort_t* ctx_bf = (ushort_t*)(base + 50331648);        //  6,291,456
    ushort_t* w_bf   = (ushort_t*)(base + 56623104);        //    327,680
    float*    part   = tmp;                                 // 4 MB
    float*    part2  = (float*)(base + 12582912 + 8388608); // 128 KB
    (void)ws_size;

    ushort_t* w_in  = w_bf;            // [2][384][128]
    ushort_t* w_out = w_bf + 98304;    // [2][128][128]
    ushort_t* w_f1  = w_bf + 131072;   // [2][64][128]
    ushort_t* w_f2  = w_bf + 147456;   // [2][128][64]

    // merged cast (320 blocks) + embed (3072 blocks, 8 rows each)
    cast_embed_kernel<<<NCAST + ROWS / 8, 512, 0, stream>>>(
        in_proj_w, 98304, out_proj_w, 32768, ffn_w1, 16384, ffn_w2, 16384,
        w_in, w_out, w_f1, w_f2,
        x, prototypes, emb_w, emb_b, proj_w, proj_b, seq, seq_bf);

    for (int l = 0; l < 2; ++l) {
        gemm_qkv<<<dim3(6, 192), 256, 0, stream>>>(
            seq_bf, w_in + (size_t)l * 49152, in_proj_b + l * 384,
            q_bf, k2, v2);
        attention_mfma<<<dim3(BB * HH, 6), 256, 0, stream>>>(q_bf, k2, v2, ctx_bf);
        // seq = LN2(LN1(seq + ctx@Wout^T + b) + FFN(...)) fully fused
        gemm_ln_ffn<<<ROWS / 64, 256, 0, stream>>>(
            ctx_bf, w_out + (size_t)l * 16384, out_proj_b + l * 128,
            ln1_s + l * EE, ln1_b + l * EE,
            w_f1 + (size_t)l * 8192, ffn_b1 + l * II,
            w_f2 + (size_t)l * 8192, ffn_b2 + l * EE,
            ln2_s + l * EE, ln2_b + l * EE,
            seq, seq_bf, l == 0 ? 1 : 0);
    }

    out_gemm3<<<PNBLK, 256, 0, stream>>>(seq_bf, out_w, part);
    out_reduce1<<<128, 256, 0, stream>>>(part, part2);
    out_reduce2<<<BB * OUTN / 256, 256, 0, stream>>>(part2, out_b, out);
}